// Round 1
// baseline (98.080 us; speedup 1.0000x reference)
//
#include <hip/hip_runtime.h>

// Element ids
#define E_EMPTY  0
#define E_WALL   1
#define E_SAND   2
#define E_WATER  3
#define E_GAS    4
#define E_WOOD   5
#define E_ICE    6
#define E_FIRE   7
#define E_PLANT  8
#define E_STONE  9
#define E_LAVA   10
#define E_ACID   11
#define E_DUST   12
#define E_CLONER 13

#define CH 18
#define HW (512*512)          // 2^18
#define NPIX (4*HW)
#define NWORLD (4*CH*HW)

__constant__ float c_dens[14] = {0.f,5.f,3.f,2.f,-1.f,5.f,5.f,0.f,5.f,4.f,3.f,2.f,3.f,5.f};
__constant__ float c_grav[14] = {1.f,0.f,1.f,1.f,1.f,0.f,1.f,1.f,0.f,1.f,1.f,1.f,1.f,0.f};

__device__ __forceinline__ int widx(int b, int y, int x) {
  return b*HW + ((y & 511) << 9) + (x & 511);   // wrap (jnp.roll semantics)
}
__device__ __forceinline__ bool is_block_e(int e) {
  return !(e==E_EMPTY || e==E_WALL || e==E_ACID || e==E_CLONER);
}
__device__ __forceinline__ bool is_burnable_e(int e) {
  return e==E_WOOD || e==E_PLANT || e==E_GAS || e==E_DUST;
}

// ---- K1: compress one-hot world -> element id (u8). mom/ca are exactly 0 in input.
__global__ void k_compress(const float* __restrict__ w, unsigned char* __restrict__ e0) {
  int g = blockIdx.x * blockDim.x + threadIdx.x;
  int base = g << 2;
  if (base >= NPIX) return;
  int b = base >> 18;
  int r = base & (HW - 1);
  const float* wb = w + (size_t)b * CH * HW + r;
  float sx=0.f, sy=0.f, sz=0.f, sw=0.f;
  #pragma unroll
  for (int c = 1; c < 14; ++c) {
    float4 v = *reinterpret_cast<const float4*>(wb + (size_t)c * HW);
    float fc = (float)c;
    sx += fc*v.x; sy += fc*v.y; sz += fc*v.z; sw += fc*v.w;
  }
  uchar4 e;
  e.x = (unsigned char)(sx + 0.5f);
  e.y = (unsigned char)(sy + 0.5f);
  e.z = (unsigned char)(sz + 0.5f);
  e.w = (unsigned char)(sw + 0.5f);
  *reinterpret_cast<uchar4*>(e0 + base) = e;
}

// ---- K2: acid (vertical wrap neighbors)
__global__ void k_acid(const unsigned char* __restrict__ e0, const float* __restrict__ ri,
                       unsigned char* __restrict__ eA) {
  int i = blockIdx.x * blockDim.x + threadIdx.x;
  if (i >= NPIX) return;
  int b = i >> 18, r = i & (HW-1), y = r >> 9, x = r & 511;
  int iu = widx(b, y-1, x), id_ = widx(b, y+1, x);
  int ec = e0[i], eu = e0[iu], ed = e0[id_];
  bool arc = ri[i]  < 0.2f;
  bool aru = ri[iu] < 0.2f;
  bool ard = ri[id_] < 0.2f;
  bool does_acid  = (ec == E_ACID) && arc && (is_block_e(ed) || is_block_e(eu));
  bool does_block = is_block_e(ec) && ((aru && eu == E_ACID) || (ard && ed == E_ACID));
  eA[i] = (does_acid || does_block) ? E_EMPTY : (unsigned char)ec;
}

// ---- K3: fire part 1 -> e1 + bfn/dfn flags packed in one byte
__global__ void k_fire1(const unsigned char* __restrict__ eA, const float* __restrict__ ri,
                        unsigned char* __restrict__ b1) {
  int i = blockIdx.x * blockDim.x + threadIdx.x;
  if (i >= NPIX) return;
  int b = i >> 18, r = i & (HW-1), y = r >> 9, x = r & 511;
  // has_fire_nb: conv3x3 (ZERO-padded, in-image only) of FIRE+LAVA indicator
  bool hfn = false;
  #pragma unroll
  for (int dy = -1; dy <= 1; ++dy) {
    int yy = y + dy; if ((unsigned)yy >= 512u) continue;
    #pragma unroll
    for (int dx = -1; dx <= 1; ++dx) {
      int xx = x + dx; if ((unsigned)xx >= 512u) continue;
      int q = eA[b*HW + (yy<<9) + xx];
      hfn = hfn || (q == E_FIRE) || (q == E_LAVA);
    }
  }
  int ec = eA[i];
  float burn = ri[i];
  bool db = (ec==E_WOOD  && burn < 0.05f) ||
            (ec==E_PLANT && burn < 0.2f)  ||
            (ec==E_GAS   && burn < 0.2f)  ||
            (ec==E_DUST);
  bool does_burn = db && hfn;
  bool db_ice = (ec==E_ICE) && (burn < 0.2f) && hfn;
  int e1 = does_burn ? E_FIRE : (db_ice ? E_WATER : ec);
  int bfn = does_burn ? 1 : 0;
  int dfn = (ec==E_DUST && hfn) ? 1 : 0;
  b1[i] = (unsigned char)(e1 | (bfn << 4) | (dfn << 5));
}

// ---- K4: velocity update (wrap shifts), written straight to d_out velocity region.
// Exact FP addition order of the reference is preserved for bit-compatibility.
__global__ void k_vel(const unsigned char* __restrict__ b1, const float* __restrict__ vin,
                      float* __restrict__ vout) {
  int i = blockIdx.x * blockDim.x + threadIdx.x;
  if (i >= NPIX) return;
  int b = i >> 18, r = i & (HW-1), y = r >> 9, x = r & 511;
  int fu = b1[widx(b, y-1, x)];
  int fd = b1[widx(b, y+1, x)];
  int fl = b1[widx(b, y, x-1)];
  int fr = b1[widx(b, y, x+1)];
  float bu = (float)((fu >> 4) & 1), bd = (float)((fd >> 4) & 1);
  float bl = (float)((fl >> 4) & 1), br = (float)((fr >> 4) & 1);
  float du = (float)((fu >> 5) & 1), dd = (float)((fd >> 5) & 1);
  float dl = (float)((fl >> 5) & 1), dr = (float)((fr >> 5) & 1);
  float vy = vin[(b*2 + 0)*HW + r];
  vy = vy + 2.0f*bu;  vy = vy - 2.0f*bd;  vy = vy + 20.0f*du;  vy = vy - 20.0f*dd;
  float vx = vin[(b*2 + 1)*HW + r];
  vx = vx + 2.0f*bl;  vx = vx - 2.0f*br;  vx = vx + 20.0f*dl;  vx = vx - 20.0f*dr;
  vout[(b*2 + 0)*HW + r] = vy;
  vout[(b*2 + 1)*HW + r] = vx;
}

// ---- K5a: has_burnable_nb = conv3x3 (zero-pad) of burnable(e1)
__global__ void k_hbn(const unsigned char* __restrict__ b1, unsigned char* __restrict__ hb) {
  int i = blockIdx.x * blockDim.x + threadIdx.x;
  if (i >= NPIX) return;
  int b = i >> 18, r = i & (HW-1), y = r >> 9, x = r & 511;
  int cnt = 0;
  #pragma unroll
  for (int dy = -1; dy <= 1; ++dy) {
    int yy = y + dy; if ((unsigned)yy >= 512u) continue;
    #pragma unroll
    for (int dx = -1; dx <= 1; ++dx) {
      int xx = x + dx; if ((unsigned)xx >= 512u) continue;
      int e1 = b1[b*HW + (yy<<9) + xx] & 15;
      cnt += is_burnable_e(e1) ? 1 : 0;
    }
  }
  hb[i] = (unsigned char)cnt;
}

// ---- K5b: fire part 2: ignition of empties + extinction of isolated fire
__global__ void k_fire2(const unsigned char* __restrict__ b1, const unsigned char* __restrict__ hb,
                        const unsigned char* __restrict__ eA, const float* __restrict__ ri,
                        const float* __restrict__ re, unsigned char* __restrict__ eF) {
  int i = blockIdx.x * blockDim.x + threadIdx.x;
  if (i >= NPIX) return;
  int b = i >> 18, r = i & (HW-1), y = r >> 9, x = r & 511;
  // in_fire_range = conv3x3( hbn * fire_and_lava(orig=eA) + (e1==LAVA) ), zero-pad
  int ifr = 0;
  #pragma unroll
  for (int dy = -1; dy <= 1; ++dy) {
    int yy = y + dy; if ((unsigned)yy >= 512u) continue;
    #pragma unroll
    for (int dx = -1; dx <= 1; ++dx) {
      int xx = x + dx; if ((unsigned)xx >= 512u) continue;
      int q = b*HW + (yy<<9) + xx;
      int e1q = b1[q] & 15;
      int eaq = eA[q];
      int flq = ((eaq == E_FIRE) || (eaq == E_LAVA)) ? 1 : 0;
      ifr += (int)hb[q] * flq + ((e1q == E_LAVA) ? 1 : 0);
    }
  }
  int e1 = b1[i] & 15;
  bool db_empty = (e1 == E_EMPTY) && (ifr > 0) && (ri[i] < 0.3f);
  int e2 = db_empty ? E_FIRE : e1;
  bool fire_empty = (e2 == E_FIRE) && (re[i] < 0.4f) && (hb[i] == 0);
  eF[i] = fire_empty ? E_EMPTY : (unsigned char)e2;
}

// ---- K6: fluid flow, one block per row, 10 sequential sub-steps in LDS.
// world ch16 (fluid_mom) is identically 0 through this phase (input is 0, swaps keep 0),
// so fall_dir = rand_movement + new_mom > 0.5.
__global__ __launch_bounds__(512) void k_fluid(const unsigned char* __restrict__ eF,
                                               const float* __restrict__ rm,
                                               const float* __restrict__ dg,
                                               unsigned char* __restrict__ eL,
                                               float* __restrict__ nmG) {
  __shared__ unsigned char e_s[512];
  __shared__ float nm_s[512];
  __shared__ unsigned char fd_s[512];
  __shared__ unsigned char nd_s[512];
  int row = blockIdx.x;
  int b = row >> 9, y = row & 511;
  int x = threadIdx.x;
  int i = b*HW + (y << 9) + x;
  e_s[x] = eF[i];
  nm_s[x] = 0.f;
  nd_s[x] = (dg[i] <= 0.f) ? 1 : 0;
  float rmx = rm[i];
  __syncthreads();
  const int elems[5] = {E_EMPTY, E_WATER, E_GAS, E_LAVA, E_ACID};
  for (int ei = 0; ei < 5; ++ei) {
    int el = elems[ei];
    #pragma unroll
    for (int fl = 1; fl >= 0; --fl) {
      fd_s[x] = (rmx + nm_s[x] > 0.5f) ? 1 : 0;
      __syncthreads();                               // fd visible; prev e writes visible
      int xl = (x + 511) & 511, xr = (x + 1) & 511;
      int ec = e_s[x], eLt = e_s[xl], eRt = e_s[xr];
      float Dc = c_dens[ec], Dl = c_dens[eLt], Dr = c_dens[eRt];
      bool gc = c_grav[ec] != 0.f, gl = c_grav[eLt] != 0.f, gr = c_grav[eRt] != 0.f;
      bool ndc = nd_s[x] != 0, ndl = nd_s[xl] != 0, ndr = nd_s[xr] != 0;
      bool fc = fd_s[x] != 0, fLt = fd_s[xl] != 0, fRt = fd_s[xr] != 0;
      int newe = ec;
      float nmadd = 0.f;
      if (fl) {   // fall_left: gdir=left, gnot=right
        bool dbl = fc  && (ec  == el) && ndc && (Dc > Dl) && gl && gc;
        bool dbr = fRt && (eRt == el) && ndr && (Dr > Dc) && gr && gc;
        if (dbr) nmadd = 2.f;
        newe = dbl ? eLt : (dbr ? eRt : ec);
      } else {    // fall_right: gdir=right, gnot=left
        bool dbl = !fc  && (ec  == el) && ndc && (Dc > Dr) && gr && gc;
        bool dbr = !fLt && (eLt == el) && ndl && (Dl > Dc) && gl && gc;
        if (dbr) nmadd = -2.f;
        newe = dbl ? eRt : (dbr ? eLt : ec);
      }
      __syncthreads();                               // all reads of e_s done
      e_s[x] = (unsigned char)newe;
      nm_s[x] += nmadd;                              // positional, own-thread only
    }
  }
  __syncthreads();
  eL[i] = e_s[x];
  nmG[i] = nm_s[x];
}

// ---- K7: cloner + expand compact state back to the 18-channel world in d_out.
// ca is 0 everywhere at cloner entry; the 4 sequential assignment passes reduce to a
// per-pixel chain over static labels; the 4 sequential spawn passes reduce to
// "first of (below, above, left, right) with an assigned cloner wins".
__device__ __forceinline__ int caF_of(const unsigned char* __restrict__ eL, int b, int y, int x) {
  int c = 0;  // entering ca == 0 -> "empty"
  int l = eL[widx(b, y+1, x)]; if (c == 0 || c == 13) c = l;
  l = eL[widx(b, y-1, x)];     if (c == 0 || c == 13) c = l;
  l = eL[widx(b, y, x-1)];     if (c == 0 || c == 13) c = l;
  l = eL[widx(b, y, x+1)];     if (c == 0 || c == 13) c = l;
  return c;
}

__global__ void k_cloner_out(const unsigned char* __restrict__ eL, const float* __restrict__ nmG,
                             float* __restrict__ out) {
  int i = blockIdx.x * blockDim.x + threadIdx.x;
  if (i >= NPIX) return;
  int b = i >> 18, r = i & (HW-1), y = r >> 9, x = r & 511;
  int ec = eL[i];
  float mom = nmG[i];
  int eo = ec;
  float cao = 0.f;
  if (ec == E_CLONER) {
    cao = (float)caF_of(eL, b, y, x);
  } else if (ec == E_EMPTY) {
    const int dy[4] = {1, -1, 0, 0};
    const int dx[4] = {0, 0, -1, 1};
    for (int d = 0; d < 4; ++d) {
      int qy = y + dy[d], qx = x + dx[d];
      if (eL[widx(b, qy, qx)] == E_CLONER) {
        int cq = caF_of(eL, b, qy, qx);
        if (cq != 0 && cq != 13) { eo = cq; mom = 0.f; break; }  // spawned: full vec replace
      }
    }
  }
  float* ob = out + (size_t)b * CH * HW + r;
  #pragma unroll
  for (int c = 0; c < 14; ++c) ob[(size_t)c * HW] = (c == eo) ? 1.f : 0.f;
  ob[(size_t)14 * HW] = c_dens[eo];
  ob[(size_t)15 * HW] = c_grav[eo];
  ob[(size_t)16 * HW] = mom;
  ob[(size_t)17 * HW] = cao;
}

extern "C" void kernel_launch(void* const* d_in, const int* in_sizes, int n_in,
                              void* d_out, int out_size, void* d_ws, size_t ws_size,
                              hipStream_t stream) {
  const float* world = (const float*)d_in[0];
  const float* rm    = (const float*)d_in[1];
  const float* ri    = (const float*)d_in[2];
  const float* re    = (const float*)d_in[3];
  const float* vel   = (const float*)d_in[4];
  const float* dg    = (const float*)d_in[5];
  float* out = (float*)d_out;

  char* ws = (char*)d_ws;
  float* nm          = (float*)ws;                          // 4 MB
  unsigned char* e0  = (unsigned char*)(ws + 4*(size_t)NPIX);
  unsigned char* eA  = e0 + NPIX;
  unsigned char* b1  = eA + NPIX;
  unsigned char* hb  = b1 + NPIX;
  unsigned char* eF  = hb + NPIX;
  unsigned char* eL  = eF + NPIX;

  dim3 blk(256);
  dim3 nb(NPIX / 256);

  hipLaunchKernelGGL(k_compress,   dim3(NPIX / (256*4)), blk, 0, stream, world, e0);
  hipLaunchKernelGGL(k_acid,       nb, blk, 0, stream, e0, ri, eA);
  hipLaunchKernelGGL(k_fire1,      nb, blk, 0, stream, eA, ri, b1);
  hipLaunchKernelGGL(k_vel,        nb, blk, 0, stream, b1, vel, out + NWORLD);
  hipLaunchKernelGGL(k_hbn,        nb, blk, 0, stream, b1, hb);
  hipLaunchKernelGGL(k_fire2,      nb, blk, 0, stream, b1, hb, eA, ri, re, eF);
  hipLaunchKernelGGL(k_fluid,      dim3(4*512), dim3(512), 0, stream, eF, rm, dg, eL, nm);
  hipLaunchKernelGGL(k_cloner_out, nb, blk, 0, stream, eL, nm, out);
}

// Round 2
// 89.217 us; speedup vs baseline: 1.0993x; 1.0993x over previous
//
#include <hip/hip_runtime.h>

// Element ids
#define E_EMPTY  0
#define E_WALL   1
#define E_SAND   2
#define E_WATER  3
#define E_GAS    4
#define E_WOOD   5
#define E_ICE    6
#define E_FIRE   7
#define E_PLANT  8
#define E_STONE  9
#define E_LAVA   10
#define E_ACID   11
#define E_DUST   12
#define E_CLONER 13

#define CH 18
#define HW (512*512)          // 2^18
#define NPIX (4*HW)
#define NWORLD (4*CH*HW)

#define ROWS 4                // output rows per k_mega block
#define R0  (ROWS+8)          // e0 region rows  [-4, ROWS+4)
#define RA  (ROWS+6)          // eA region rows  [-3, ROWS+3)
#define RB  (ROWS+4)          // b1 region rows  [-2, ROWS+2)
#define RHB (ROWS+2)          // hb region rows  [-1, ROWS+1)

__constant__ float c_dens[14] = {0.f,5.f,3.f,2.f,-1.f,5.f,5.f,0.f,5.f,4.f,3.f,2.f,3.f,5.f};
__constant__ float c_grav[14] = {1.f,0.f,1.f,1.f,1.f,0.f,1.f,1.f,0.f,1.f,1.f,1.f,1.f,0.f};

__device__ __forceinline__ bool is_block_e(int e) {
  return !(e==E_EMPTY || e==E_WALL || e==E_ACID || e==E_CLONER);
}
__device__ __forceinline__ int is_burnable_e(int e) {
  return (e==E_WOOD || e==E_PLANT || e==E_GAS || e==E_DUST) ? 1 : 0;
}

// ---- K1: decode one-hot world -> u8 element id, reading only 9 planes.
// (D,G) splits {EMPTY,FIRE}/{WALL,WOOD,PLANT,CLONER}/{SAND,LAVA,DUST}/{WATER,ACID}/ICE/STONE/GAS;
// FIRE,WALL,WOOD,PLANT,SAND,LAVA,WATER channels disambiguate.
__device__ __forceinline__ unsigned char decode1(float d, float g, float f, float wa,
                                                 float wo, float pl, float sa, float lv, float wt) {
  if (g < 0.5f) {
    if (wa > 0.5f) return E_WALL;
    if (wo > 0.5f) return E_WOOD;
    if (pl > 0.5f) return E_PLANT;
    return E_CLONER;
  }
  int di = (int)d;          // d in {-1,0,2,3,4,5}, exact
  if (di == 0) return (f > 0.5f) ? E_FIRE : E_EMPTY;
  if (di == 5) return E_ICE;
  if (di == 4) return E_STONE;
  if (di < 0)  return E_GAS;
  if (di == 3) { if (sa > 0.5f) return E_SAND; if (lv > 0.5f) return E_LAVA; return E_DUST; }
  return (wt > 0.5f) ? E_WATER : E_ACID;
}

__global__ __launch_bounds__(256) void k_compress9(const float* __restrict__ w,
                                                   unsigned char* __restrict__ e0) {
  int g = blockIdx.x * 256 + threadIdx.x;
  int base = g << 2;
  int b = base >> 18;
  int r = base & (HW - 1);
  const float* wb = w + (size_t)b * CH * HW + r;
  float4 D  = *reinterpret_cast<const float4*>(wb + (size_t)14 * HW);
  float4 G  = *reinterpret_cast<const float4*>(wb + (size_t)15 * HW);
  float4 F  = *reinterpret_cast<const float4*>(wb + (size_t)7  * HW);
  float4 WA = *reinterpret_cast<const float4*>(wb + (size_t)1  * HW);
  float4 WO = *reinterpret_cast<const float4*>(wb + (size_t)5  * HW);
  float4 PL = *reinterpret_cast<const float4*>(wb + (size_t)8  * HW);
  float4 SA = *reinterpret_cast<const float4*>(wb + (size_t)2  * HW);
  float4 LV = *reinterpret_cast<const float4*>(wb + (size_t)10 * HW);
  float4 WT = *reinterpret_cast<const float4*>(wb + (size_t)3  * HW);
  uchar4 e;
  e.x = decode1(D.x, G.x, F.x, WA.x, WO.x, PL.x, SA.x, LV.x, WT.x);
  e.y = decode1(D.y, G.y, F.y, WA.y, WO.y, PL.y, SA.y, LV.y, WT.y);
  e.z = decode1(D.z, G.z, F.z, WA.z, WO.z, PL.z, SA.z, LV.z, WT.z);
  e.w = decode1(D.w, G.w, F.w, WA.w, WO.w, PL.w, SA.w, LV.w, WT.w);
  *reinterpret_cast<uchar4*>(e0 + base) = e;
}

// ---- K2: fused acid + fire1 + velocity + hbn + fire2 + fluid-flow.
// One block owns ROWS full-width rows; vertical halo cascade staged in LDS with wrap;
// conv3x3 masks use absolute coords (zero-pad), roll ops use the wrapped staging.
__global__ __launch_bounds__(512) void k_mega(const unsigned char* __restrict__ e0g,
                                              const float* __restrict__ ri,
                                              const float* __restrict__ re,
                                              const float* __restrict__ rm,
                                              const float* __restrict__ dg,
                                              const float* __restrict__ vin,
                                              unsigned char* __restrict__ eLg,
                                              signed char* __restrict__ nmg,
                                              float* __restrict__ vout) {
  __shared__ unsigned char e0s[R0][512];
  __shared__ unsigned char rcs[R0][512];   // bit0: ri<0.05, bit1: ri<0.2, bit2: ri<0.3
  __shared__ unsigned char eas[RA][512];
  __shared__ unsigned char b1s[RB][512];   // e1 | bfn<<4 | dfn<<5
  __shared__ unsigned char hbs[RHB][512];
  __shared__ unsigned char efs[ROWS][512];
  __shared__ unsigned char fds[ROWS][512];
  __shared__ unsigned char nds[ROWS][512];

  int blk = blockIdx.x;
  int b  = blk >> 7;                 // 128 row-tiles per batch (512/ROWS)
  int ty = (blk & 127) * ROWS;
  int x  = threadIdx.x;              // absolute column
  int bbase = b * HW;

  // Stage e0 + ri threshold bits for the full region (wrapped rows).
  #pragma unroll
  for (int l = 0; l < R0; ++l) {
    int gy = (ty + l - 4) & 511;
    int gi = bbase + (gy << 9) + x;
    e0s[l][x] = e0g[gi];
    float rv = ri[gi];
    rcs[l][x] = (unsigned char)((rv < 0.05f ? 1 : 0) | (rv < 0.2f ? 2 : 0) | (rv < 0.3f ? 4 : 0));
  }
  // Fluid-phase per-cell state for the output rows.
  float rmx[ROWS], nmv[ROWS];
  #pragma unroll
  for (int r_ = 0; r_ < ROWS; ++r_) {
    int gi = bbase + ((ty + r_) << 9) + x;
    rmx[r_] = rm[gi];
    nmv[r_] = 0.f;
    nds[r_][x] = (dg[gi] <= 0.f) ? 1 : 0;
  }
  __syncthreads();

  // ---- acid (vertical wrap neighbors): eA row l covers global (ty+l-3)&511
  #pragma unroll
  for (int l = 0; l < RA; ++l) {
    int ec = e0s[l+1][x], eu = e0s[l][x], ed = e0s[l+2][x];
    bool arc = (rcs[l+1][x] & 2) != 0;
    bool aru = (rcs[l][x]   & 2) != 0;
    bool ard = (rcs[l+2][x] & 2) != 0;
    bool does_acid  = (ec == E_ACID) && arc && (is_block_e(ed) || is_block_e(eu));
    bool does_block = is_block_e(ec) && ((aru && eu == E_ACID) || (ard && ed == E_ACID));
    eas[l][x] = (does_acid || does_block) ? (unsigned char)E_EMPTY : (unsigned char)ec;
  }
  __syncthreads();

  // ---- fire1 -> b1 (conv3x3 zero-pad on fire+lava of eA)
  #pragma unroll
  for (int l = 0; l < RB; ++l) {
    int gy = (ty + l - 2) & 511;
    bool hfn = false;
    #pragma unroll
    for (int dy = -1; dy <= 1; ++dy) {
      int yy = gy + dy; if ((unsigned)yy >= 512u) continue;
      #pragma unroll
      for (int dx = -1; dx <= 1; ++dx) {
        int xx = x + dx; if ((unsigned)xx >= 512u) continue;
        int q = eas[l+1+dy][xx];
        hfn = hfn || (q == E_FIRE) || (q == E_LAVA);
      }
    }
    int ec = eas[l+1][x];
    int rc = rcs[l+2][x];
    bool db = (ec==E_WOOD && (rc&1)) || (ec==E_PLANT && (rc&2)) ||
              (ec==E_GAS  && (rc&2)) || (ec==E_DUST);
    bool does_burn = db && hfn;
    bool db_ice = (ec==E_ICE) && (rc&2) && hfn;
    int e1 = does_burn ? E_FIRE : (db_ice ? E_WATER : ec);
    int flag = (does_burn ? 16 : 0) | ((ec==E_DUST && hfn) ? 32 : 0);
    b1s[l][x] = (unsigned char)(e1 | flag);
  }
  __syncthreads();

  // ---- hbn = conv3x3 zero-pad of burnable(e1)
  #pragma unroll
  for (int l = 0; l < RHB; ++l) {
    int gy = (ty + l - 1) & 511;
    int cnt = 0;
    #pragma unroll
    for (int dy = -1; dy <= 1; ++dy) {
      int yy = gy + dy; if ((unsigned)yy >= 512u) continue;
      #pragma unroll
      for (int dx = -1; dx <= 1; ++dx) {
        int xx = x + dx; if ((unsigned)xx >= 512u) continue;
        cnt += is_burnable_e(b1s[l+1+dy][xx] & 15);
      }
    }
    hbs[l][x] = (unsigned char)cnt;
  }
  __syncthreads();

  // ---- fire2 -> efs ; velocity -> vout (wrap shifts, exact FP order)
  #pragma unroll
  for (int l = 0; l < ROWS; ++l) {
    int gy = ty + l;                   // always in-image
    int ifr = 0;
    #pragma unroll
    for (int dy = -1; dy <= 1; ++dy) {
      int yy = gy + dy; if ((unsigned)yy >= 512u) continue;
      #pragma unroll
      for (int dx = -1; dx <= 1; ++dx) {
        int xx = x + dx; if ((unsigned)xx >= 512u) continue;
        int hbq = hbs[l+1+dy][xx];
        int eaq = eas[l+3+dy][xx];
        int e1q = b1s[l+2+dy][xx] & 15;
        int flq = (eaq == E_FIRE || eaq == E_LAVA) ? 1 : 0;
        ifr += hbq * flq + ((e1q == E_LAVA) ? 1 : 0);
      }
    }
    int e1 = b1s[l+2][x] & 15;
    bool db_empty = (e1 == E_EMPTY) && (ifr > 0) && ((rcs[l+4][x] & 4) != 0);
    int e2 = db_empty ? E_FIRE : e1;
    int gi = bbase + (gy << 9) + x;
    bool fire_empty = (e2 == E_FIRE) && (re[gi] < 0.4f) && (hbs[l+1][x] == 0);
    efs[l][x] = fire_empty ? (unsigned char)E_EMPTY : (unsigned char)e2;

    int fu  = b1s[l+1][x];
    int fd_ = b1s[l+3][x];
    int flf = b1s[l+2][(x+511)&511];
    int frt = b1s[l+2][(x+1)&511];
    float vy = vin[(size_t)(b*2+0)*HW + (gy<<9) + x];
    vy = vy + 2.0f*(float)((fu>>4)&1);  vy = vy - 2.0f*(float)((fd_>>4)&1);
    vy = vy + 20.0f*(float)((fu>>5)&1); vy = vy - 20.0f*(float)((fd_>>5)&1);
    float vx = vin[(size_t)(b*2+1)*HW + (gy<<9) + x];
    vx = vx + 2.0f*(float)((flf>>4)&1);  vx = vx - 2.0f*(float)((frt>>4)&1);
    vx = vx + 20.0f*(float)((flf>>5)&1); vx = vx - 20.0f*(float)((frt>>5)&1);
    vout[(size_t)(b*2+0)*HW + (gy<<9) + x] = vy;
    vout[(size_t)(b*2+1)*HW + (gy<<9) + x] = vx;
  }
  __syncthreads();

  // ---- fluid flow: 5 elements x 2 directions, purely horizontal, in LDS.
  const int elems[5] = {E_EMPTY, E_WATER, E_GAS, E_LAVA, E_ACID};
  int xl = (x + 511) & 511, xr = (x + 1) & 511;
  for (int ei = 0; ei < 5; ++ei) {
    int el = elems[ei];
    #pragma unroll
    for (int fl = 1; fl >= 0; --fl) {
      #pragma unroll
      for (int r_ = 0; r_ < ROWS; ++r_)
        fds[r_][x] = (rmx[r_] + nmv[r_] > 0.5f) ? 1 : 0;
      __syncthreads();
      int newe[ROWS]; float nmadd[ROWS];
      #pragma unroll
      for (int r_ = 0; r_ < ROWS; ++r_) {
        int ec  = efs[r_][x], eLt = efs[r_][xl], eRt = efs[r_][xr];
        float Dc = c_dens[ec], Dl = c_dens[eLt], Dr = c_dens[eRt];
        bool gc = c_grav[ec] != 0.f, gl = c_grav[eLt] != 0.f, gr = c_grav[eRt] != 0.f;
        bool ndc = nds[r_][x] != 0, ndl = nds[r_][xl] != 0, ndr = nds[r_][xr] != 0;
        bool fc = fds[r_][x] != 0, fLt = fds[r_][xl] != 0, fRt = fds[r_][xr] != 0;
        int ne = ec; float na = 0.f;
        if (fl) {       // fall_left: gdir=left, gnot=right
          bool dbl = fc  && (ec  == el) && ndc && (Dc > Dl) && gl && gc;
          bool dbr = fRt && (eRt == el) && ndr && (Dr > Dc) && gr && gc;
          if (dbr) na = 2.f;
          ne = dbl ? eLt : (dbr ? eRt : ec);
        } else {        // fall_right: gdir=right, gnot=left
          bool dbl = !fc  && (ec  == el) && ndc && (Dc > Dr) && gr && gc;
          bool dbr = !fLt && (eLt == el) && ndl && (Dl > Dc) && gl && gc;
          if (dbr) na = -2.f;
          ne = dbl ? eRt : (dbr ? eLt : ec);
        }
        newe[r_] = ne; nmadd[r_] = na;
      }
      __syncthreads();
      #pragma unroll
      for (int r_ = 0; r_ < ROWS; ++r_) {
        efs[r_][x] = (unsigned char)newe[r_];
        nmv[r_] += nmadd[r_];
      }
    }
  }
  __syncthreads();
  #pragma unroll
  for (int r_ = 0; r_ < ROWS; ++r_) {
    int gi = bbase + ((ty + r_) << 9) + x;
    eLg[gi] = efs[r_][x];
    nmg[gi] = (signed char)(int)nmv[r_];
  }
}

// ---- K3: cloner + expand back to 18-channel world. 4 px/thread, float4 stores.
__device__ __forceinline__ int caF_of(const unsigned char* __restrict__ eb, int y, int x) {
  int c = eb[(((y+1)&511)<<9) + (x&511)];
  if (c == 0 || c == 13) c = eb[(((y+511)&511)<<9) + (x&511)];
  if (c == 0 || c == 13) c = eb[((y&511)<<9) + ((x+511)&511)];
  if (c == 0 || c == 13) c = eb[((y&511)<<9) + ((x+1)&511)];
  return c;
}

__global__ __launch_bounds__(256) void k_cloner_out(const unsigned char* __restrict__ eL,
                                                    const signed char* __restrict__ nm,
                                                    float* __restrict__ out) {
  int g = blockIdx.x * 256 + threadIdx.x;
  int base = g << 2;
  int b = base >> 18, r = base & (HW - 1);
  int y = r >> 9, x0 = r & 511;
  const unsigned char* eb = eL + b * HW;
  const int DY[4] = {1, -1, 0, 0};
  const int DX[4] = {0, 0, -1, 1};
  int eo[4]; float mom[4], cao[4];
  #pragma unroll
  for (int k = 0; k < 4; ++k) {
    int x = x0 + k;                     // same row, no wrap inside quad
    int ec = eb[(y<<9) + x];
    float m = (float)nm[b*HW + (y<<9) + x];
    int e = ec; float ca = 0.f;
    if (ec == E_CLONER) {
      ca = (float)caF_of(eb, y, x);
    } else if (ec == E_EMPTY) {
      #pragma unroll
      for (int d = 0; d < 4; ++d) {
        int qy = (y + DY[d]) & 511, qx = (x + DX[d]) & 511;
        if (eb[(qy<<9) + qx] == E_CLONER) {
          int cq = caF_of(eb, qy, qx);
          if (cq != 0 && cq != 13) { e = cq; m = 0.f; break; }
        }
      }
    }
    eo[k] = e; mom[k] = m; cao[k] = ca;
  }
  float* ob = out + (size_t)b * CH * HW + r;
  #pragma unroll
  for (int c = 0; c < 14; ++c) {
    float4 v = make_float4(eo[0]==c ? 1.f : 0.f, eo[1]==c ? 1.f : 0.f,
                           eo[2]==c ? 1.f : 0.f, eo[3]==c ? 1.f : 0.f);
    *reinterpret_cast<float4*>(ob + (size_t)c * HW) = v;
  }
  *reinterpret_cast<float4*>(ob + (size_t)14*HW) =
      make_float4(c_dens[eo[0]], c_dens[eo[1]], c_dens[eo[2]], c_dens[eo[3]]);
  *reinterpret_cast<float4*>(ob + (size_t)15*HW) =
      make_float4(c_grav[eo[0]], c_grav[eo[1]], c_grav[eo[2]], c_grav[eo[3]]);
  *reinterpret_cast<float4*>(ob + (size_t)16*HW) =
      make_float4(mom[0], mom[1], mom[2], mom[3]);
  *reinterpret_cast<float4*>(ob + (size_t)17*HW) =
      make_float4(cao[0], cao[1], cao[2], cao[3]);
}

extern "C" void kernel_launch(void* const* d_in, const int* in_sizes, int n_in,
                              void* d_out, int out_size, void* d_ws, size_t ws_size,
                              hipStream_t stream) {
  const float* world = (const float*)d_in[0];
  const float* rm    = (const float*)d_in[1];
  const float* ri    = (const float*)d_in[2];
  const float* re    = (const float*)d_in[3];
  const float* vel   = (const float*)d_in[4];
  const float* dg    = (const float*)d_in[5];
  float* out = (float*)d_out;

  char* ws = (char*)d_ws;
  unsigned char* e0 = (unsigned char*)ws;
  unsigned char* eL = e0 + NPIX;
  signed char*   nm = (signed char*)(eL + NPIX);

  hipLaunchKernelGGL(k_compress9, dim3(NPIX/(256*4)), dim3(256), 0, stream, world, e0);
  hipLaunchKernelGGL(k_mega, dim3(4*(512/ROWS)), dim3(512), 0, stream,
                     e0, ri, re, rm, dg, vel, eL, nm, out + NWORLD);
  hipLaunchKernelGGL(k_cloner_out, dim3(NPIX/(256*4)), dim3(256), 0, stream, eL, nm, out);
}

// Round 3
// 72.508 us; speedup vs baseline: 1.3527x; 1.2304x over previous
//
#include <hip/hip_runtime.h>

// Element ids
#define E_EMPTY  0
#define E_WALL   1
#define E_SAND   2
#define E_WATER  3
#define E_GAS    4
#define E_WOOD   5
#define E_ICE    6
#define E_FIRE   7
#define E_PLANT  8
#define E_STONE  9
#define E_LAVA   10
#define E_ACID   11
#define E_DUST   12
#define E_CLONER 13

#define CH 18
#define HW (512*512)          // 2^18
#define NPIX (4*HW)
#define NWORLD (4*CH*HW)

// dens+1 packed as nibbles (e=0..13): values {1,6,4,3,0,6,6,1,6,5,4,3,4,6}
#define PACKD 0x64345616603461ULL
// gravity bitmask: bit e set iff GRAVITY[e]==1
#define GMASK 7901
// is_block (not EMPTY/WALL/ACID/CLONER)
#define BMASK 6140
// burnable (WOOD|PLANT|GAS|DUST)
#define BURNM 4400

__constant__ float c_dens[14] = {0.f,5.f,3.f,2.f,-1.f,5.f,5.f,0.f,5.f,4.f,3.f,2.f,3.f,5.f};
__constant__ float c_grav[14] = {1.f,0.f,1.f,1.f,1.f,0.f,1.f,1.f,0.f,1.f,1.f,1.f,1.f,0.f};

__device__ __forceinline__ bool is_block_e(int e) { return (BMASK >> e) & 1; }
__device__ __forceinline__ int is_burnable_e(int e) { return (BURNM >> e) & 1; }

// ---- K1: decode one-hot world (9 planes) -> u8 id; fold all rand thresholds -> bit-pack.
// rb bits: 0: ri<0.05, 1: ri<0.2, 2: ri<0.3, 3: re<0.4, 4: rm>0.5, 5: dg<=0
__device__ __forceinline__ unsigned char decode1(float d, float g, float f, float wa,
                                                 float wo, float pl, float sa, float lv, float wt) {
  if (g < 0.5f) {
    if (wa > 0.5f) return E_WALL;
    if (wo > 0.5f) return E_WOOD;
    if (pl > 0.5f) return E_PLANT;
    return E_CLONER;
  }
  int di = (int)d;          // d in {-1,0,2,3,4,5}, exact
  if (di == 0) return (f > 0.5f) ? E_FIRE : E_EMPTY;
  if (di == 5) return E_ICE;
  if (di == 4) return E_STONE;
  if (di < 0)  return E_GAS;
  if (di == 3) { if (sa > 0.5f) return E_SAND; if (lv > 0.5f) return E_LAVA; return E_DUST; }
  return (wt > 0.5f) ? E_WATER : E_ACID;
}

__global__ __launch_bounds__(256) void k_prep(const float* __restrict__ w,
                                              const float* __restrict__ ri,
                                              const float* __restrict__ re,
                                              const float* __restrict__ rm,
                                              const float* __restrict__ dg,
                                              unsigned char* __restrict__ e0,
                                              unsigned char* __restrict__ rb) {
  int g = blockIdx.x * 256 + threadIdx.x;
  int base = g << 2;
  int b = base >> 18;
  int r = base & (HW - 1);
  const float* wb = w + (size_t)b * CH * HW + r;
  float4 D  = *reinterpret_cast<const float4*>(wb + (size_t)14 * HW);
  float4 G  = *reinterpret_cast<const float4*>(wb + (size_t)15 * HW);
  float4 F  = *reinterpret_cast<const float4*>(wb + (size_t)7  * HW);
  float4 WA = *reinterpret_cast<const float4*>(wb + (size_t)1  * HW);
  float4 WO = *reinterpret_cast<const float4*>(wb + (size_t)5  * HW);
  float4 PL = *reinterpret_cast<const float4*>(wb + (size_t)8  * HW);
  float4 SA = *reinterpret_cast<const float4*>(wb + (size_t)2  * HW);
  float4 LV = *reinterpret_cast<const float4*>(wb + (size_t)10 * HW);
  float4 WT = *reinterpret_cast<const float4*>(wb + (size_t)3  * HW);
  uchar4 e;
  e.x = decode1(D.x, G.x, F.x, WA.x, WO.x, PL.x, SA.x, LV.x, WT.x);
  e.y = decode1(D.y, G.y, F.y, WA.y, WO.y, PL.y, SA.y, LV.y, WT.y);
  e.z = decode1(D.z, G.z, F.z, WA.z, WO.z, PL.z, SA.z, LV.z, WT.z);
  e.w = decode1(D.w, G.w, F.w, WA.w, WO.w, PL.w, SA.w, LV.w, WT.w);
  *reinterpret_cast<uchar4*>(e0 + base) = e;

  float4 RI = *reinterpret_cast<const float4*>(ri + base);
  float4 RE = *reinterpret_cast<const float4*>(re + base);
  float4 RM = *reinterpret_cast<const float4*>(rm + base);
  float4 DG = *reinterpret_cast<const float4*>(dg + base);
  uchar4 q;
  q.x = (RI.x<0.05f?1:0)|(RI.x<0.2f?2:0)|(RI.x<0.3f?4:0)|(RE.x<0.4f?8:0)|(RM.x>0.5f?16:0)|(DG.x<=0.f?32:0);
  q.y = (RI.y<0.05f?1:0)|(RI.y<0.2f?2:0)|(RI.y<0.3f?4:0)|(RE.y<0.4f?8:0)|(RM.y>0.5f?16:0)|(DG.y<=0.f?32:0);
  q.z = (RI.z<0.05f?1:0)|(RI.z<0.2f?2:0)|(RI.z<0.3f?4:0)|(RE.z<0.4f?8:0)|(RM.z>0.5f?16:0)|(DG.z<=0.f?32:0);
  q.w = (RI.w<0.05f?1:0)|(RI.w<0.2f?2:0)|(RI.w<0.3f?4:0)|(RE.w<0.4f?8:0)|(RM.w>0.5f?16:0)|(DG.w<=0.f?32:0);
  *reinterpret_cast<uchar4*>(rb + base) = q;
}

// ---- K2: fused acid + fire1 + velocity + hbn + fire2, 2D tiles 128x8, 4 barriers.
#define TW 128
#define TH 8
#define E0R (TH+8)   // 16
#define E0C (TW+6)   // 134
#define EAR (TH+6)   // 14
#define EAC (TW+6)   // 134
#define B1R (TH+4)   // 12
#define B1C (TW+4)   // 132
#define HBR (TH+2)   // 10
#define HBC (TW+2)   // 130

__global__ __launch_bounds__(256) void k_stencil(const unsigned char* __restrict__ e0g,
                                                 const unsigned char* __restrict__ rbg,
                                                 const float* __restrict__ vin,
                                                 unsigned char* __restrict__ efg,
                                                 float* __restrict__ vout) {
  __shared__ unsigned char e0s[E0R][E0C];
  __shared__ unsigned char rbs[E0R][E0C];
  __shared__ unsigned char eas[EAR][EAC];
  __shared__ unsigned char b1s[B1R][B1C];
  __shared__ unsigned char hbs[HBR][HBC];

  int tid = threadIdx.x;
  int blk = blockIdx.x;
  int b = blk >> 8;                  // 256 tiles per batch
  int t = blk & 255;
  int ty = (t >> 2) * TH;
  int tx = (t & 3) * TW;
  int bbase = b * HW;

  // stage e0 + rb over the full halo region (wrapped)
  for (int idx = tid; idx < E0R*E0C; idx += 256) {
    int l = idx / E0C, c = idx - l * E0C;
    int gy = (ty + l - 4) & 511, gx = (tx + c - 3) & 511;
    int gi = bbase + (gy << 9) + gx;
    e0s[l][c] = e0g[gi];
    rbs[l][c] = rbg[gi];
  }
  __syncthreads();

  // acid: eA row l covers abs (ty+l-3), col c covers (tx+c-3). vertical-only stencil.
  for (int idx = tid; idx < EAR*EAC; idx += 256) {
    int l = idx / EAC, c = idx - l * EAC;
    int ec = e0s[l+1][c], eu = e0s[l][c], ed = e0s[l+2][c];
    bool arc = (rbs[l+1][c] & 2) != 0;
    bool aru = (rbs[l][c]   & 2) != 0;
    bool ard = (rbs[l+2][c] & 2) != 0;
    bool does_acid  = (ec == E_ACID) && arc && (is_block_e(ed) || is_block_e(eu));
    bool does_block = is_block_e(ec) && ((aru && eu == E_ACID) || (ard && ed == E_ACID));
    eas[l][c] = (does_acid || does_block) ? (unsigned char)E_EMPTY : (unsigned char)ec;
  }
  __syncthreads();

  // fire1 -> b1 (e1 | bfn<<4 | dfn<<5). b1 row l abs (ty+l-2), col c abs (tx+c-2).
  for (int idx = tid; idx < B1R*B1C; idx += 256) {
    int l = idx / B1C, c = idx - l * B1C;
    int gy = (ty + l - 2) & 511, gx = (tx + c - 2) & 511;
    bool hfn = false;
    #pragma unroll
    for (int dy = -1; dy <= 1; ++dy) {
      int yy = gy + dy; if ((unsigned)yy >= 512u) continue;
      #pragma unroll
      for (int dx = -1; dx <= 1; ++dx) {
        int xx = gx + dx; if ((unsigned)xx >= 512u) continue;
        int q = eas[l+1+dy][c+1+dx];
        hfn = hfn || (q == E_FIRE) || (q == E_LAVA);
      }
    }
    int ec = eas[l+1][c+1];
    int rbv = rbs[l+2][c+1];
    bool db = (ec==E_WOOD && (rbv&1)) || (ec==E_PLANT && (rbv&2)) ||
              (ec==E_GAS  && (rbv&2)) || (ec==E_DUST);
    bool does_burn = db && hfn;
    bool db_ice = (ec==E_ICE) && (rbv&2) && hfn;
    int e1 = does_burn ? E_FIRE : (db_ice ? E_WATER : ec);
    b1s[l][c] = (unsigned char)(e1 | (does_burn?16:0) | ((ec==E_DUST && hfn)?32:0));
  }
  __syncthreads();

  // hbn: row l abs (ty+l-1), col c abs (tx+c-1)
  for (int idx = tid; idx < HBR*HBC; idx += 256) {
    int l = idx / HBC, c = idx - l * HBC;
    int gy = (ty + l - 1) & 511, gx = (tx + c - 1) & 511;
    int cnt = 0;
    #pragma unroll
    for (int dy = -1; dy <= 1; ++dy) {
      int yy = gy + dy; if ((unsigned)yy >= 512u) continue;
      #pragma unroll
      for (int dx = -1; dx <= 1; ++dx) {
        int xx = gx + dx; if ((unsigned)xx >= 512u) continue;
        cnt += is_burnable_e(b1s[l+1+dy][c+1+dx] & 15);
      }
    }
    hbs[l][c] = (unsigned char)cnt;
  }
  __syncthreads();

  // fire2 + velocity at output pixels
  for (int k = tid; k < TH*TW; k += 256) {
    int oy = k >> 7, ox = k & 127;
    int gy = ty + oy, gx = tx + ox;
    int gi = bbase + (gy << 9) + gx;
    int ifr = 0;
    #pragma unroll
    for (int dy = -1; dy <= 1; ++dy) {
      int yy = gy + dy; if ((unsigned)yy >= 512u) continue;
      #pragma unroll
      for (int dx = -1; dx <= 1; ++dx) {
        int xx = gx + dx; if ((unsigned)xx >= 512u) continue;
        int hbq = hbs[oy+1+dy][ox+1+dx];
        int eaq = eas[oy+3+dy][ox+3+dx];
        int e1q = b1s[oy+2+dy][ox+2+dx] & 15;
        ifr += hbq * (((eaq==E_FIRE)||(eaq==E_LAVA))?1:0) + ((e1q==E_LAVA)?1:0);
      }
    }
    int e1 = b1s[oy+2][ox+2] & 15;
    int rbv = rbs[oy+4][ox+3];
    bool db_empty = (e1 == E_EMPTY) && (ifr > 0) && ((rbv & 4) != 0);
    int e2 = db_empty ? E_FIRE : e1;
    bool fire_empty = (e2 == E_FIRE) && ((rbv & 8) != 0) && (hbs[oy+1][ox+1] == 0);
    efg[gi] = fire_empty ? (unsigned char)E_EMPTY : (unsigned char)e2;

    int fu  = b1s[oy+1][ox+2];
    int fd_ = b1s[oy+3][ox+2];
    int flf = b1s[oy+2][ox+1];
    int frt = b1s[oy+2][ox+3];
    float vy = vin[(size_t)(b*2+0)*HW + (gy<<9) + gx];
    vy = vy + 2.0f*(float)((fu>>4)&1);   vy = vy - 2.0f*(float)((fd_>>4)&1);
    vy = vy + 20.0f*(float)((fu>>5)&1);  vy = vy - 20.0f*(float)((fd_>>5)&1);
    float vx = vin[(size_t)(b*2+1)*HW + (gy<<9) + gx];
    vx = vx + 2.0f*(float)((flf>>4)&1);  vx = vx - 2.0f*(float)((frt>>4)&1);
    vx = vx + 20.0f*(float)((flf>>5)&1); vx = vx - 20.0f*(float)((frt>>5)&1);
    vout[(size_t)(b*2+0)*HW + (gy<<9) + gx] = vy;
    vout[(size_t)(b*2+1)*HW + (gy<<9) + gx] = vx;
  }
}

// ---- K3: fluid flow. One wave per row, 8 cells/lane, all in registers, 0 barriers.
// fall_dir = rm + mom > 0.5 with mom an even int  <=>  mom>0 || (mom==0 && rm>0.5). Exact.
__global__ __launch_bounds__(256) void k_fluid(const unsigned char* __restrict__ efg,
                                               const unsigned char* __restrict__ rbg,
                                               unsigned char* __restrict__ eLg,
                                               signed char* __restrict__ nmg) {
  int gid = blockIdx.x * 256 + threadIdx.x;
  int wv = gid >> 6, lane = gid & 63;
  int b = wv >> 9, y = wv & 511;
  int base = b*HW + (y << 9) + (lane << 3);

  uchar4 ea = *reinterpret_cast<const uchar4*>(efg + base);
  uchar4 eb = *reinterpret_cast<const uchar4*>(efg + base + 4);
  int e[8] = {ea.x, ea.y, ea.z, ea.w, eb.x, eb.y, eb.z, eb.w};
  uchar4 qa = *reinterpret_cast<const uchar4*>(rbg + base);
  uchar4 qb = *reinterpret_cast<const uchar4*>(rbg + base + 4);
  int rmb = ((qa.x>>4)&1) | (((qa.y>>4)&1)<<1) | (((qa.z>>4)&1)<<2) | (((qa.w>>4)&1)<<3)
          | (((qb.x>>4)&1)<<4) | (((qb.y>>4)&1)<<5) | (((qb.z>>4)&1)<<6) | (((qb.w>>4)&1)<<7);
  int ndb = ((qa.x>>5)&1) | (((qa.y>>5)&1)<<1) | (((qa.z>>5)&1)<<2) | (((qa.w>>5)&1)<<3)
          | (((qb.x>>5)&1)<<4) | (((qb.y>>5)&1)<<5) | (((qb.z>>5)&1)<<6) | (((qb.w>>5)&1)<<7);
  int mom[8] = {0,0,0,0,0,0,0,0};

  int laneL = (lane + 63) & 63, laneR = (lane + 1) & 63;
  int ndl = (__shfl(ndb, laneL, 64) >> 7) & 1;     // nd of cell x0-1
  int ndr =  __shfl(ndb, laneR, 64) & 1;           // nd of cell x0+8

  const int elems[5] = {E_EMPTY, E_WATER, E_GAS, E_LAVA, E_ACID};
  #pragma unroll
  for (int ei = 0; ei < 5; ++ei) {
    int el = elems[ei];
    #pragma unroll
    for (int fl = 1; fl >= 0; --fl) {
      int fdb = 0;
      #pragma unroll
      for (int j = 0; j < 8; ++j)
        fdb |= ((mom[j] > 0 || (mom[j] == 0 && ((rmb >> j) & 1))) ? 1 : 0) << j;
      int myR = e[7] | (((fdb >> 7) & 1) << 8);
      int myL = e[0] | ((fdb & 1) << 8);
      int pl_ = __shfl(myR, laneL, 64);
      int pr_ = __shfl(myL, laneR, 64);
      int eBL = pl_ & 255, fBL = (pl_ >> 8) & 1;
      int eBR = pr_ & 255, fBR = (pr_ >> 8) & 1;
      int ne[8];
      #pragma unroll
      for (int j = 0; j < 8; ++j) {
        int ec  = e[j];
        int eL_ = j ? e[j-1] : eBL;
        int eR_ = (j < 7) ? e[j+1] : eBR;
        int fc  = (fdb >> j) & 1;
        int fL_ = j ? ((fdb >> (j-1)) & 1) : fBL;
        int fR_ = (j < 7) ? ((fdb >> (j+1)) & 1) : fBR;
        int nc  = (ndb >> j) & 1;
        int nl  = j ? ((ndb >> (j-1)) & 1) : ndl;
        int nr  = (j < 7) ? ((ndb >> (j+1)) & 1) : ndr;
        int dc = (int)((PACKD >> (ec  * 4)) & 15);
        int dl = (int)((PACKD >> (eL_ * 4)) & 15);
        int dr = (int)((PACKD >> (eR_ * 4)) & 15);
        int gc = (GMASK >> ec) & 1, gl = (GMASK >> eL_) & 1, gr = (GMASK >> eR_) & 1;
        int nn = ec;
        if (fl) {   // fall_left
          bool dbl = fc  && (ec  == el) && nc && (dc > dl) && gl && gc;
          bool dbr = fR_ && (eR_ == el) && nr && (dr > dc) && gr && gc;
          if (dbr) mom[j] += 2;
          nn = dbl ? eL_ : (dbr ? eR_ : ec);
        } else {    // fall_right
          bool dbl = !fc  && (ec  == el) && nc && (dc > dr) && gr && gc;
          bool dbr = !fL_ && (eL_ == el) && nl && (dl > dc) && gl && gc;
          if (dbr) mom[j] -= 2;
          nn = dbl ? eR_ : (dbr ? eL_ : ec);
        }
        ne[j] = nn;
      }
      #pragma unroll
      for (int j = 0; j < 8; ++j) e[j] = ne[j];
    }
  }

  unsigned int w0 = (unsigned)e[0] | ((unsigned)e[1]<<8) | ((unsigned)e[2]<<16) | ((unsigned)e[3]<<24);
  unsigned int w1 = (unsigned)e[4] | ((unsigned)e[5]<<8) | ((unsigned)e[6]<<16) | ((unsigned)e[7]<<24);
  *reinterpret_cast<uint2*>(eLg + base) = make_uint2(w0, w1);
  unsigned int m0 = (mom[0]&255) | ((mom[1]&255)<<8) | ((mom[2]&255)<<16) | ((unsigned)(mom[3]&255)<<24);
  unsigned int m1 = (mom[4]&255) | ((mom[5]&255)<<8) | ((mom[6]&255)<<16) | ((unsigned)(mom[7]&255)<<24);
  *reinterpret_cast<uint2*>(reinterpret_cast<unsigned char*>(nmg) + base) = make_uint2(m0, m1);
}

// ---- K4: cloner + expand back to 18-channel world. 4 px/thread, float4 stores.
__device__ __forceinline__ int caF_of(const unsigned char* __restrict__ eb, int y, int x) {
  int c = eb[(((y+1)&511)<<9) + (x&511)];
  if (c == 0 || c == 13) c = eb[(((y+511)&511)<<9) + (x&511)];
  if (c == 0 || c == 13) c = eb[((y&511)<<9) + ((x+511)&511)];
  if (c == 0 || c == 13) c = eb[((y&511)<<9) + ((x+1)&511)];
  return c;
}

__global__ __launch_bounds__(256) void k_cloner_out(const unsigned char* __restrict__ eL,
                                                    const signed char* __restrict__ nm,
                                                    float* __restrict__ out) {
  int g = blockIdx.x * 256 + threadIdx.x;
  int base = g << 2;
  int b = base >> 18, r = base & (HW - 1);
  int y = r >> 9, x0 = r & 511;
  const unsigned char* eb = eL + b * HW;
  const int DY[4] = {1, -1, 0, 0};
  const int DX[4] = {0, 0, -1, 1};
  int eo[4]; float mom[4], cao[4];
  #pragma unroll
  for (int k = 0; k < 4; ++k) {
    int x = x0 + k;                     // same row, no wrap inside quad
    int ec = eb[(y<<9) + x];
    float m = (float)nm[b*HW + (y<<9) + x];
    int e = ec; float ca = 0.f;
    if (ec == E_CLONER) {
      ca = (float)caF_of(eb, y, x);
    } else if (ec == E_EMPTY) {
      #pragma unroll
      for (int d = 0; d < 4; ++d) {
        int qy = (y + DY[d]) & 511, qx = (x + DX[d]) & 511;
        if (eb[(qy<<9) + qx] == E_CLONER) {
          int cq = caF_of(eb, qy, qx);
          if (cq != 0 && cq != 13) { e = cq; m = 0.f; break; }
        }
      }
    }
    eo[k] = e; mom[k] = m; cao[k] = ca;
  }
  float* ob = out + (size_t)b * CH * HW + r;
  #pragma unroll
  for (int c = 0; c < 14; ++c) {
    float4 v = make_float4(eo[0]==c ? 1.f : 0.f, eo[1]==c ? 1.f : 0.f,
                           eo[2]==c ? 1.f : 0.f, eo[3]==c ? 1.f : 0.f);
    *reinterpret_cast<float4*>(ob + (size_t)c * HW) = v;
  }
  *reinterpret_cast<float4*>(ob + (size_t)14*HW) =
      make_float4(c_dens[eo[0]], c_dens[eo[1]], c_dens[eo[2]], c_dens[eo[3]]);
  *reinterpret_cast<float4*>(ob + (size_t)15*HW) =
      make_float4(c_grav[eo[0]], c_grav[eo[1]], c_grav[eo[2]], c_grav[eo[3]]);
  *reinterpret_cast<float4*>(ob + (size_t)16*HW) =
      make_float4(mom[0], mom[1], mom[2], mom[3]);
  *reinterpret_cast<float4*>(ob + (size_t)17*HW) =
      make_float4(cao[0], cao[1], cao[2], cao[3]);
}

extern "C" void kernel_launch(void* const* d_in, const int* in_sizes, int n_in,
                              void* d_out, int out_size, void* d_ws, size_t ws_size,
                              hipStream_t stream) {
  const float* world = (const float*)d_in[0];
  const float* rm    = (const float*)d_in[1];
  const float* ri    = (const float*)d_in[2];
  const float* re    = (const float*)d_in[3];
  const float* vel   = (const float*)d_in[4];
  const float* dg    = (const float*)d_in[5];
  float* out = (float*)d_out;

  char* ws = (char*)d_ws;
  unsigned char* e0 = (unsigned char*)ws;
  unsigned char* rb = e0 + NPIX;
  unsigned char* eF = rb + NPIX;
  unsigned char* eL = eF + NPIX;
  signed char*   nm = (signed char*)(eL + NPIX);

  hipLaunchKernelGGL(k_prep,    dim3(NPIX/1024), dim3(256), 0, stream,
                     world, ri, re, rm, dg, e0, rb);
  hipLaunchKernelGGL(k_stencil, dim3(1024), dim3(256), 0, stream,
                     e0, rb, vel, eF, out + NWORLD);
  hipLaunchKernelGGL(k_fluid,   dim3(512), dim3(256), 0, stream, eF, rb, eL, nm);
  hipLaunchKernelGGL(k_cloner_out, dim3(NPIX/1024), dim3(256), 0, stream, eL, nm, out);
}

// Round 4
// 69.623 us; speedup vs baseline: 1.4087x; 1.0414x over previous
//
#include <hip/hip_runtime.h>

// Element ids
#define E_EMPTY  0
#define E_WALL   1
#define E_SAND   2
#define E_WATER  3
#define E_GAS    4
#define E_WOOD   5
#define E_ICE    6
#define E_FIRE   7
#define E_PLANT  8
#define E_STONE  9
#define E_LAVA   10
#define E_ACID   11
#define E_DUST   12
#define E_CLONER 13

#define CH 18
#define HW (512*512)          // 2^18
#define NPIX (4*HW)
#define NWORLD (4*CH*HW)

// dens+1 packed as nibbles (e=0..13): values {1,6,4,3,0,6,6,1,6,5,4,3,4,6}
#define PACKD 0x64345616603461ULL
// gravity bitmask: bit e set iff GRAVITY[e]==1
#define GMASK 7901
// is_block (not EMPTY/WALL/ACID/CLONER)
#define BMASK 6140
// burnable (WOOD|PLANT|GAS|DUST)
#define BURNM 4400

__constant__ float c_dens[14] = {0.f,5.f,3.f,2.f,-1.f,5.f,5.f,0.f,5.f,4.f,3.f,2.f,3.f,5.f};
__constant__ float c_grav[14] = {1.f,0.f,1.f,1.f,1.f,0.f,1.f,1.f,0.f,1.f,1.f,1.f,1.f,0.f};

__device__ __forceinline__ bool is_block_e(int e) { return (BMASK >> e) & 1; }
__device__ __forceinline__ int is_burnable_e(int e) { return (BURNM >> e) & 1; }

// ---- K1: decode one-hot world (9 planes) -> u8 id; fold all rand thresholds -> bit-pack.
// rb bits: 0: ri<0.05, 1: ri<0.2, 2: ri<0.3, 3: re<0.4, 4: rm>0.5, 5: dg<=0
__device__ __forceinline__ unsigned char decode1(float d, float g, float f, float wa,
                                                 float wo, float pl, float sa, float lv, float wt) {
  if (g < 0.5f) {
    if (wa > 0.5f) return E_WALL;
    if (wo > 0.5f) return E_WOOD;
    if (pl > 0.5f) return E_PLANT;
    return E_CLONER;
  }
  int di = (int)d;          // d in {-1,0,2,3,4,5}, exact
  if (di == 0) return (f > 0.5f) ? E_FIRE : E_EMPTY;
  if (di == 5) return E_ICE;
  if (di == 4) return E_STONE;
  if (di < 0)  return E_GAS;
  if (di == 3) { if (sa > 0.5f) return E_SAND; if (lv > 0.5f) return E_LAVA; return E_DUST; }
  return (wt > 0.5f) ? E_WATER : E_ACID;
}

__global__ __launch_bounds__(256) void k_prep(const float* __restrict__ w,
                                              const float* __restrict__ ri,
                                              const float* __restrict__ re,
                                              const float* __restrict__ rm,
                                              const float* __restrict__ dg,
                                              unsigned char* __restrict__ e0,
                                              unsigned char* __restrict__ rb) {
  int g = blockIdx.x * 256 + threadIdx.x;
  int base = g << 2;
  int b = base >> 18;
  int r = base & (HW - 1);
  const float* wb = w + (size_t)b * CH * HW + r;
  float4 D  = *reinterpret_cast<const float4*>(wb + (size_t)14 * HW);
  float4 G  = *reinterpret_cast<const float4*>(wb + (size_t)15 * HW);
  float4 F  = *reinterpret_cast<const float4*>(wb + (size_t)7  * HW);
  float4 WA = *reinterpret_cast<const float4*>(wb + (size_t)1  * HW);
  float4 WO = *reinterpret_cast<const float4*>(wb + (size_t)5  * HW);
  float4 PL = *reinterpret_cast<const float4*>(wb + (size_t)8  * HW);
  float4 SA = *reinterpret_cast<const float4*>(wb + (size_t)2  * HW);
  float4 LV = *reinterpret_cast<const float4*>(wb + (size_t)10 * HW);
  float4 WT = *reinterpret_cast<const float4*>(wb + (size_t)3  * HW);
  uchar4 e;
  e.x = decode1(D.x, G.x, F.x, WA.x, WO.x, PL.x, SA.x, LV.x, WT.x);
  e.y = decode1(D.y, G.y, F.y, WA.y, WO.y, PL.y, SA.y, LV.y, WT.y);
  e.z = decode1(D.z, G.z, F.z, WA.z, WO.z, PL.z, SA.z, LV.z, WT.z);
  e.w = decode1(D.w, G.w, F.w, WA.w, WO.w, PL.w, SA.w, LV.w, WT.w);
  *reinterpret_cast<uchar4*>(e0 + base) = e;

  float4 RI = *reinterpret_cast<const float4*>(ri + base);
  float4 RE = *reinterpret_cast<const float4*>(re + base);
  float4 RM = *reinterpret_cast<const float4*>(rm + base);
  float4 DG = *reinterpret_cast<const float4*>(dg + base);
  uchar4 q;
  q.x = (RI.x<0.05f?1:0)|(RI.x<0.2f?2:0)|(RI.x<0.3f?4:0)|(RE.x<0.4f?8:0)|(RM.x>0.5f?16:0)|(DG.x<=0.f?32:0);
  q.y = (RI.y<0.05f?1:0)|(RI.y<0.2f?2:0)|(RI.y<0.3f?4:0)|(RE.y<0.4f?8:0)|(RM.y>0.5f?16:0)|(DG.y<=0.f?32:0);
  q.z = (RI.z<0.05f?1:0)|(RI.z<0.2f?2:0)|(RI.z<0.3f?4:0)|(RE.z<0.4f?8:0)|(RM.z>0.5f?16:0)|(DG.z<=0.f?32:0);
  q.w = (RI.w<0.05f?1:0)|(RI.w<0.2f?2:0)|(RI.w<0.3f?4:0)|(RE.w<0.4f?8:0)|(RM.w>0.5f?16:0)|(DG.w<=0.f?32:0);
  *reinterpret_cast<uchar4*>(rb + base) = q;
}

// ---- K2: fused acid + fire1 + velocity + hbn + fire2, 2D tiles 128x8, 4 barriers.
#define TW 128
#define TH 8
#define E0R (TH+8)   // 16
#define E0C (TW+6)   // 134
#define EAR (TH+6)   // 14
#define EAC (TW+6)   // 134
#define B1R (TH+4)   // 12
#define B1C (TW+4)   // 132
#define HBR (TH+2)   // 10
#define HBC (TW+2)   // 130

__global__ __launch_bounds__(256) void k_stencil(const unsigned char* __restrict__ e0g,
                                                 const unsigned char* __restrict__ rbg,
                                                 const float* __restrict__ vin,
                                                 unsigned char* __restrict__ efg,
                                                 float* __restrict__ vout) {
  __shared__ unsigned char e0s[E0R][E0C];
  __shared__ unsigned char rbs[E0R][E0C];
  __shared__ unsigned char eas[EAR][EAC];
  __shared__ unsigned char b1s[B1R][B1C];
  __shared__ unsigned char hbs[HBR][HBC];

  int tid = threadIdx.x;
  int blk = blockIdx.x;
  int b = blk >> 8;                  // 256 tiles per batch
  int t = blk & 255;
  int ty = (t >> 2) * TH;
  int tx = (t & 3) * TW;
  int bbase = b * HW;

  // stage e0 + rb over the full halo region (wrapped)
  for (int idx = tid; idx < E0R*E0C; idx += 256) {
    int l = idx / E0C, c = idx - l * E0C;
    int gy = (ty + l - 4) & 511, gx = (tx + c - 3) & 511;
    int gi = bbase + (gy << 9) + gx;
    e0s[l][c] = e0g[gi];
    rbs[l][c] = rbg[gi];
  }
  __syncthreads();

  // acid: eA row l covers abs (ty+l-3), col c covers (tx+c-3). vertical-only stencil.
  for (int idx = tid; idx < EAR*EAC; idx += 256) {
    int l = idx / EAC, c = idx - l * EAC;
    int ec = e0s[l+1][c], eu = e0s[l][c], ed = e0s[l+2][c];
    bool arc = (rbs[l+1][c] & 2) != 0;
    bool aru = (rbs[l][c]   & 2) != 0;
    bool ard = (rbs[l+2][c] & 2) != 0;
    bool does_acid  = (ec == E_ACID) && arc && (is_block_e(ed) || is_block_e(eu));
    bool does_block = is_block_e(ec) && ((aru && eu == E_ACID) || (ard && ed == E_ACID));
    eas[l][c] = (does_acid || does_block) ? (unsigned char)E_EMPTY : (unsigned char)ec;
  }
  __syncthreads();

  // fire1 -> b1 (e1 | bfn<<4 | dfn<<5). b1 row l abs (ty+l-2), col c abs (tx+c-2).
  for (int idx = tid; idx < B1R*B1C; idx += 256) {
    int l = idx / B1C, c = idx - l * B1C;
    int gy = (ty + l - 2) & 511, gx = (tx + c - 2) & 511;
    bool hfn = false;
    #pragma unroll
    for (int dy = -1; dy <= 1; ++dy) {
      int yy = gy + dy; if ((unsigned)yy >= 512u) continue;
      #pragma unroll
      for (int dx = -1; dx <= 1; ++dx) {
        int xx = gx + dx; if ((unsigned)xx >= 512u) continue;
        int q = eas[l+1+dy][c+1+dx];
        hfn = hfn || (q == E_FIRE) || (q == E_LAVA);
      }
    }
    int ec = eas[l+1][c+1];
    int rbv = rbs[l+2][c+1];
    bool db = (ec==E_WOOD && (rbv&1)) || (ec==E_PLANT && (rbv&2)) ||
              (ec==E_GAS  && (rbv&2)) || (ec==E_DUST);
    bool does_burn = db && hfn;
    bool db_ice = (ec==E_ICE) && (rbv&2) && hfn;
    int e1 = does_burn ? E_FIRE : (db_ice ? E_WATER : ec);
    b1s[l][c] = (unsigned char)(e1 | (does_burn?16:0) | ((ec==E_DUST && hfn)?32:0));
  }
  __syncthreads();

  // hbn: row l abs (ty+l-1), col c abs (tx+c-1)
  for (int idx = tid; idx < HBR*HBC; idx += 256) {
    int l = idx / HBC, c = idx - l * HBC;
    int gy = (ty + l - 1) & 511, gx = (tx + c - 1) & 511;
    int cnt = 0;
    #pragma unroll
    for (int dy = -1; dy <= 1; ++dy) {
      int yy = gy + dy; if ((unsigned)yy >= 512u) continue;
      #pragma unroll
      for (int dx = -1; dx <= 1; ++dx) {
        int xx = gx + dx; if ((unsigned)xx >= 512u) continue;
        cnt += is_burnable_e(b1s[l+1+dy][c+1+dx] & 15);
      }
    }
    hbs[l][c] = (unsigned char)cnt;
  }
  __syncthreads();

  // fire2 + velocity at output pixels
  for (int k = tid; k < TH*TW; k += 256) {
    int oy = k >> 7, ox = k & 127;
    int gy = ty + oy, gx = tx + ox;
    int gi = bbase + (gy << 9) + gx;
    int ifr = 0;
    #pragma unroll
    for (int dy = -1; dy <= 1; ++dy) {
      int yy = gy + dy; if ((unsigned)yy >= 512u) continue;
      #pragma unroll
      for (int dx = -1; dx <= 1; ++dx) {
        int xx = gx + dx; if ((unsigned)xx >= 512u) continue;
        int hbq = hbs[oy+1+dy][ox+1+dx];
        int eaq = eas[oy+3+dy][ox+3+dx];
        int e1q = b1s[oy+2+dy][ox+2+dx] & 15;
        ifr += hbq * (((eaq==E_FIRE)||(eaq==E_LAVA))?1:0) + ((e1q==E_LAVA)?1:0);
      }
    }
    int e1 = b1s[oy+2][ox+2] & 15;
    int rbv = rbs[oy+4][ox+3];
    bool db_empty = (e1 == E_EMPTY) && (ifr > 0) && ((rbv & 4) != 0);
    int e2 = db_empty ? E_FIRE : e1;
    bool fire_empty = (e2 == E_FIRE) && ((rbv & 8) != 0) && (hbs[oy+1][ox+1] == 0);
    efg[gi] = fire_empty ? (unsigned char)E_EMPTY : (unsigned char)e2;

    int fu  = b1s[oy+1][ox+2];
    int fd_ = b1s[oy+3][ox+2];
    int flf = b1s[oy+2][ox+1];
    int frt = b1s[oy+2][ox+3];
    float vy = vin[(size_t)(b*2+0)*HW + (gy<<9) + gx];
    vy = vy + 2.0f*(float)((fu>>4)&1);   vy = vy - 2.0f*(float)((fd_>>4)&1);
    vy = vy + 20.0f*(float)((fu>>5)&1);  vy = vy - 20.0f*(float)((fd_>>5)&1);
    float vx = vin[(size_t)(b*2+1)*HW + (gy<<9) + gx];
    vx = vx + 2.0f*(float)((flf>>4)&1);  vx = vx - 2.0f*(float)((frt>>4)&1);
    vx = vx + 20.0f*(float)((flf>>5)&1); vx = vx - 20.0f*(float)((frt>>5)&1);
    vout[(size_t)(b*2+0)*HW + (gy<<9) + gx] = vy;
    vout[(size_t)(b*2+1)*HW + (gy<<9) + gx] = vx;
  }
}

// ---- K3: fluid flow. One wave per row, 8 cells/lane, NAMED SCALARS ONLY (no arrays
// -> no scratch). props: density-nibble | gravity<<4, from packed 64-bit constant.
#define PROPS(E) ((int)((PACKD >> ((E)*4)) & 15) | ((((GMASK) >> (E)) & 1) << 4))
#define FD(M,BIT) (((M) > 0 || ((M) == 0 && ((rmb >> (BIT)) & 1))) ? 1 : 0)

// fall_left: dbl = fc & (ec==el) & nd_c & (d_c>d_w) & g_w & g_c ; swap with west
//            dbr = f_e & (e_e==el) & nd_e & (d_e>d_c) & g_e & g_c ; swap with east, mom+=2
#define STEPL(NEW,EC,EW,EE,PC,PW,PE,FC,FE,NDC,NDE,MOM) { \
  bool dbl = (FC) && ((EC)==el) && (NDC) && (((PC)&15) > ((PW)&15)) && ((PW)&16) && ((PC)&16); \
  bool dbr = (FE) && ((EE)==el) && (NDE) && (((PE)&15) > ((PC)&15)) && ((PE)&16) && ((PC)&16); \
  MOM += dbr ? 2 : 0; \
  NEW = dbl ? (EW) : (dbr ? (EE) : (EC)); }

// fall_right: dbl = !fc & (ec==el) & nd_c & (d_c>d_e) & g_e & g_c ; swap with east
//             dbr = !f_w & (e_w==el) & nd_w & (d_w>d_c) & g_w & g_c ; swap with west, mom-=2
#define STEPR(NEW,EC,EW,EE,PC,PW,PE,FC,FW,NDC,NDW,MOM) { \
  bool dbl = !(FC) && ((EC)==el) && (NDC) && (((PC)&15) > ((PE)&15)) && ((PE)&16) && ((PC)&16); \
  bool dbr = !(FW) && ((EW)==el) && (NDW) && (((PW)&15) > ((PC)&15)) && ((PW)&16) && ((PC)&16); \
  MOM -= dbr ? 2 : 0; \
  NEW = dbl ? (EE) : (dbr ? (EW) : (EC)); }

#define FDEF int f0=FD(M0,0), f1=FD(M1,1), f2=FD(M2,2), f3=FD(M3,3), \
                 f4=FD(M4,4), f5=FD(M5,5), f6=FD(M6,6), f7=FD(M7,7)
#define PDEF int P0=PROPS(E0), P1=PROPS(E1), P2=PROPS(E2), P3=PROPS(E3), \
                 P4=PROPS(E4), P5=PROPS(E5), P6=PROPS(E6), P7=PROPS(E7)

__global__ __launch_bounds__(256) void k_fluid(const unsigned char* __restrict__ efg,
                                               const unsigned char* __restrict__ rbg,
                                               unsigned char* __restrict__ eLg,
                                               signed char* __restrict__ nmg) {
  int gid = blockIdx.x * 256 + threadIdx.x;
  int wv = gid >> 6, lane = gid & 63;
  int b = wv >> 9, y = wv & 511;
  int base = b*HW + (y << 9) + (lane << 3);

  uint2 ev = *reinterpret_cast<const uint2*>(efg + base);
  int E0 =  ev.x        & 255, E1 = (ev.x >> 8) & 255,
      E2 = (ev.x >> 16) & 255, E3 = (ev.x >> 24) & 255,
      E4 =  ev.y        & 255, E5 = (ev.y >> 8) & 255,
      E6 = (ev.y >> 16) & 255, E7 = (ev.y >> 24) & 255;
  uint2 qv = *reinterpret_cast<const uint2*>(rbg + base);
  int rmb = ((qv.x>>4)&1) | (((qv.x>>12)&1)<<1) | (((qv.x>>20)&1)<<2) | (((qv.x>>28)&1)<<3)
          | (((qv.y>>4)&1)<<4) | (((qv.y>>12)&1)<<5) | (((qv.y>>20)&1)<<6) | (((qv.y>>28)&1)<<7);
  int nd0 = (qv.x>>5)&1,  nd1 = (qv.x>>13)&1, nd2 = (qv.x>>21)&1, nd3 = (qv.x>>29)&1,
      nd4 = (qv.y>>5)&1,  nd5 = (qv.y>>13)&1, nd6 = (qv.y>>21)&1, nd7 = (qv.y>>29)&1;
  int M0=0,M1=0,M2=0,M3=0,M4=0,M5=0,M6=0,M7=0;

  int laneL = (lane + 63) & 63, laneR = (lane + 1) & 63;
  int ndpk = nd0 | (nd7 << 1);
  int ndl = (__shfl(ndpk, laneL, 64) >> 1) & 1;   // nd of cell west of E0
  int ndr =  __shfl(ndpk, laneR, 64) & 1;         // nd of cell east of E7

  #pragma unroll
  for (int ei = 0; ei < 5; ++ei) {
    const int el = (ei==0) ? E_EMPTY : (ei==1) ? E_WATER : (ei==2) ? E_GAS
                 : (ei==3) ? E_LAVA  : E_ACID;
    { // fall_left
      FDEF;
      int pl_ = __shfl(E7 | (f7 << 8), laneL, 64);
      int pr_ = __shfl(E0 | (f0 << 8), laneR, 64);
      int EBL = pl_ & 255;
      int EBR = pr_ & 255, FBR = (pr_ >> 8) & 1;
      int PBL = PROPS(EBL), PBR = PROPS(EBR);
      PDEF;
      int N0,N1,N2,N3,N4,N5,N6,N7;
      STEPL(N0,E0,EBL,E1,P0,PBL,P1,f0,f1, nd0,nd1,M0);
      STEPL(N1,E1,E0, E2,P1,P0, P2,f1,f2, nd1,nd2,M1);
      STEPL(N2,E2,E1, E3,P2,P1, P3,f2,f3, nd2,nd3,M2);
      STEPL(N3,E3,E2, E4,P3,P2, P4,f3,f4, nd3,nd4,M3);
      STEPL(N4,E4,E3, E5,P4,P3, P5,f4,f5, nd4,nd5,M4);
      STEPL(N5,E5,E4, E6,P5,P4, P6,f5,f6, nd5,nd6,M5);
      STEPL(N6,E6,E5, E7,P6,P5, P7,f6,f7, nd6,nd7,M6);
      STEPL(N7,E7,E6,EBR,P7,P6,PBR,f7,FBR,nd7,ndr,M7);
      E0=N0; E1=N1; E2=N2; E3=N3; E4=N4; E5=N5; E6=N6; E7=N7;
    }
    { // fall_right
      FDEF;
      int pl_ = __shfl(E7 | (f7 << 8), laneL, 64);
      int pr_ = __shfl(E0 | (f0 << 8), laneR, 64);
      int EBL = pl_ & 255, FBL = (pl_ >> 8) & 1;
      int EBR = pr_ & 255;
      int PBL = PROPS(EBL), PBR = PROPS(EBR);
      PDEF;
      int N0,N1,N2,N3,N4,N5,N6,N7;
      STEPR(N0,E0,EBL,E1,P0,PBL,P1,f0,FBL,nd0,ndl,M0);
      STEPR(N1,E1,E0, E2,P1,P0, P2,f1,f0, nd1,nd0,M1);
      STEPR(N2,E2,E1, E3,P2,P1, P3,f2,f1, nd2,nd1,M2);
      STEPR(N3,E3,E2, E4,P3,P2, P4,f3,f2, nd3,nd2,M3);
      STEPR(N4,E4,E3, E5,P4,P3, P5,f4,f3, nd4,nd3,M4);
      STEPR(N5,E5,E4, E6,P5,P4, P6,f5,f4, nd5,nd4,M5);
      STEPR(N6,E6,E5, E7,P6,P5, P7,f6,f5, nd6,nd5,M6);
      STEPR(N7,E7,E6,EBR,P7,P6,PBR,f7,f6, nd7,nd6,M7);
      E0=N0; E1=N1; E2=N2; E3=N3; E4=N4; E5=N5; E6=N6; E7=N7;
    }
  }

  unsigned int w0 = (unsigned)E0 | ((unsigned)E1<<8) | ((unsigned)E2<<16) | ((unsigned)E3<<24);
  unsigned int w1 = (unsigned)E4 | ((unsigned)E5<<8) | ((unsigned)E6<<16) | ((unsigned)E7<<24);
  *reinterpret_cast<uint2*>(eLg + base) = make_uint2(w0, w1);
  unsigned int m0 = (M0&255) | ((M1&255)<<8) | ((M2&255)<<16) | ((unsigned)(M3&255)<<24);
  unsigned int m1 = (M4&255) | ((M5&255)<<8) | ((M6&255)<<16) | ((unsigned)(M7&255)<<24);
  *reinterpret_cast<uint2*>(reinterpret_cast<unsigned char*>(nmg) + base) = make_uint2(m0, m1);
}

// ---- K4: cloner + expand back to 18-channel world. 4 px/thread, float4 stores.
__device__ __forceinline__ int caF_of(const unsigned char* __restrict__ eb, int y, int x) {
  int c = eb[(((y+1)&511)<<9) + (x&511)];
  if (c == 0 || c == 13) c = eb[(((y+511)&511)<<9) + (x&511)];
  if (c == 0 || c == 13) c = eb[((y&511)<<9) + ((x+511)&511)];
  if (c == 0 || c == 13) c = eb[((y&511)<<9) + ((x+1)&511)];
  return c;
}

__global__ __launch_bounds__(256) void k_cloner_out(const unsigned char* __restrict__ eL,
                                                    const signed char* __restrict__ nm,
                                                    float* __restrict__ out) {
  int g = blockIdx.x * 256 + threadIdx.x;
  int base = g << 2;
  int b = base >> 18, r = base & (HW - 1);
  int y = r >> 9, x0 = r & 511;
  const unsigned char* eb = eL + b * HW;
  const int DY[4] = {1, -1, 0, 0};
  const int DX[4] = {0, 0, -1, 1};
  int eo[4]; float mom[4], cao[4];
  #pragma unroll
  for (int k = 0; k < 4; ++k) {
    int x = x0 + k;                     // same row, no wrap inside quad
    int ec = eb[(y<<9) + x];
    float m = (float)nm[b*HW + (y<<9) + x];
    int e = ec; float ca = 0.f;
    if (ec == E_CLONER) {
      ca = (float)caF_of(eb, y, x);
    } else if (ec == E_EMPTY) {
      #pragma unroll
      for (int d = 0; d < 4; ++d) {
        int qy = (y + DY[d]) & 511, qx = (x + DX[d]) & 511;
        if (eb[(qy<<9) + qx] == E_CLONER) {
          int cq = caF_of(eb, qy, qx);
          if (cq != 0 && cq != 13) { e = cq; m = 0.f; break; }
        }
      }
    }
    eo[k] = e; mom[k] = m; cao[k] = ca;
  }
  float* ob = out + (size_t)b * CH * HW + r;
  #pragma unroll
  for (int c = 0; c < 14; ++c) {
    float4 v = make_float4(eo[0]==c ? 1.f : 0.f, eo[1]==c ? 1.f : 0.f,
                           eo[2]==c ? 1.f : 0.f, eo[3]==c ? 1.f : 0.f);
    *reinterpret_cast<float4*>(ob + (size_t)c * HW) = v;
  }
  *reinterpret_cast<float4*>(ob + (size_t)14*HW) =
      make_float4(c_dens[eo[0]], c_dens[eo[1]], c_dens[eo[2]], c_dens[eo[3]]);
  *reinterpret_cast<float4*>(ob + (size_t)15*HW) =
      make_float4(c_grav[eo[0]], c_grav[eo[1]], c_grav[eo[2]], c_grav[eo[3]]);
  *reinterpret_cast<float4*>(ob + (size_t)16*HW) =
      make_float4(mom[0], mom[1], mom[2], mom[3]);
  *reinterpret_cast<float4*>(ob + (size_t)17*HW) =
      make_float4(cao[0], cao[1], cao[2], cao[3]);
}

extern "C" void kernel_launch(void* const* d_in, const int* in_sizes, int n_in,
                              void* d_out, int out_size, void* d_ws, size_t ws_size,
                              hipStream_t stream) {
  const float* world = (const float*)d_in[0];
  const float* rm    = (const float*)d_in[1];
  const float* ri    = (const float*)d_in[2];
  const float* re    = (const float*)d_in[3];
  const float* vel   = (const float*)d_in[4];
  const float* dg    = (const float*)d_in[5];
  float* out = (float*)d_out;

  char* ws = (char*)d_ws;
  unsigned char* e0 = (unsigned char*)ws;
  unsigned char* rb = e0 + NPIX;
  unsigned char* eF = rb + NPIX;
  unsigned char* eL = eF + NPIX;
  signed char*   nm = (signed char*)(eL + NPIX);

  hipLaunchKernelGGL(k_prep,    dim3(NPIX/1024), dim3(256), 0, stream,
                     world, ri, re, rm, dg, e0, rb);
  hipLaunchKernelGGL(k_stencil, dim3(1024), dim3(256), 0, stream,
                     e0, rb, vel, eF, out + NWORLD);
  hipLaunchKernelGGL(k_fluid,   dim3(512), dim3(256), 0, stream, eF, rb, eL, nm);
  hipLaunchKernelGGL(k_cloner_out, dim3(NPIX/1024), dim3(256), 0, stream, eL, nm, out);
}

// Round 5
// 63.259 us; speedup vs baseline: 1.5504x; 1.1006x over previous
//
#include <hip/hip_runtime.h>

// Element ids
#define E_EMPTY  0
#define E_WALL   1
#define E_SAND   2
#define E_WATER  3
#define E_GAS    4
#define E_WOOD   5
#define E_ICE    6
#define E_FIRE   7
#define E_PLANT  8
#define E_STONE  9
#define E_LAVA   10
#define E_ACID   11
#define E_DUST   12
#define E_CLONER 13

#define CH 18
#define HW (512*512)          // 2^18
#define NPIX (4*HW)
#define NWORLD (4*CH*HW)

// dens+1 packed as nibbles (e=0..13): values {1,6,4,3,0,6,6,1,6,5,4,3,4,6}
#define PACKD 0x64345616603461ULL
// gravity bitmask: bit e set iff GRAVITY[e]==1
#define GMASK 7901
// is_block (not EMPTY/WALL/ACID/CLONER)
#define BMASK 6140
// burnable (WOOD|PLANT|GAS|DUST)
#define BURNM 4400

__constant__ float c_dens[14] = {0.f,5.f,3.f,2.f,-1.f,5.f,5.f,0.f,5.f,4.f,3.f,2.f,3.f,5.f};
__constant__ float c_grav[14] = {1.f,0.f,1.f,1.f,1.f,0.f,1.f,1.f,0.f,1.f,1.f,1.f,1.f,0.f};

__device__ __forceinline__ bool is_block_e(int e) { return (BMASK >> e) & 1; }
__device__ __forceinline__ int is_burnable_e(int e) { return (BURNM >> e) & 1; }

// ---- K1: decode one-hot world (9 planes) -> u8 id; fold all rand thresholds -> bit-pack.
// rb bits: 0: ri<0.05, 1: ri<0.2, 2: ri<0.3, 3: re<0.4, 4: rm>0.5, 5: dg<=0
__device__ __forceinline__ unsigned char decode1(float d, float g, float f, float wa,
                                                 float wo, float pl, float sa, float lv, float wt) {
  if (g < 0.5f) {
    if (wa > 0.5f) return E_WALL;
    if (wo > 0.5f) return E_WOOD;
    if (pl > 0.5f) return E_PLANT;
    return E_CLONER;
  }
  int di = (int)d;          // d in {-1,0,2,3,4,5}, exact
  if (di == 0) return (f > 0.5f) ? E_FIRE : E_EMPTY;
  if (di == 5) return E_ICE;
  if (di == 4) return E_STONE;
  if (di < 0)  return E_GAS;
  if (di == 3) { if (sa > 0.5f) return E_SAND; if (lv > 0.5f) return E_LAVA; return E_DUST; }
  return (wt > 0.5f) ? E_WATER : E_ACID;
}

__global__ __launch_bounds__(256) void k_prep(const float* __restrict__ w,
                                              const float* __restrict__ ri,
                                              const float* __restrict__ re,
                                              const float* __restrict__ rm,
                                              const float* __restrict__ dg,
                                              unsigned char* __restrict__ e0,
                                              unsigned char* __restrict__ rb) {
  int g = blockIdx.x * 256 + threadIdx.x;
  int base = g << 2;
  int b = base >> 18;
  int r = base & (HW - 1);
  const float* wb = w + (size_t)b * CH * HW + r;
  float4 D  = *reinterpret_cast<const float4*>(wb + (size_t)14 * HW);
  float4 G  = *reinterpret_cast<const float4*>(wb + (size_t)15 * HW);
  float4 F  = *reinterpret_cast<const float4*>(wb + (size_t)7  * HW);
  float4 WA = *reinterpret_cast<const float4*>(wb + (size_t)1  * HW);
  float4 WO = *reinterpret_cast<const float4*>(wb + (size_t)5  * HW);
  float4 PL = *reinterpret_cast<const float4*>(wb + (size_t)8  * HW);
  float4 SA = *reinterpret_cast<const float4*>(wb + (size_t)2  * HW);
  float4 LV = *reinterpret_cast<const float4*>(wb + (size_t)10 * HW);
  float4 WT = *reinterpret_cast<const float4*>(wb + (size_t)3  * HW);
  uchar4 e;
  e.x = decode1(D.x, G.x, F.x, WA.x, WO.x, PL.x, SA.x, LV.x, WT.x);
  e.y = decode1(D.y, G.y, F.y, WA.y, WO.y, PL.y, SA.y, LV.y, WT.y);
  e.z = decode1(D.z, G.z, F.z, WA.z, WO.z, PL.z, SA.z, LV.z, WT.z);
  e.w = decode1(D.w, G.w, F.w, WA.w, WO.w, PL.w, SA.w, LV.w, WT.w);
  *reinterpret_cast<uchar4*>(e0 + base) = e;

  float4 RI = *reinterpret_cast<const float4*>(ri + base);
  float4 RE = *reinterpret_cast<const float4*>(re + base);
  float4 RM = *reinterpret_cast<const float4*>(rm + base);
  float4 DG = *reinterpret_cast<const float4*>(dg + base);
  uchar4 q;
  q.x = (RI.x<0.05f?1:0)|(RI.x<0.2f?2:0)|(RI.x<0.3f?4:0)|(RE.x<0.4f?8:0)|(RM.x>0.5f?16:0)|(DG.x<=0.f?32:0);
  q.y = (RI.y<0.05f?1:0)|(RI.y<0.2f?2:0)|(RI.y<0.3f?4:0)|(RE.y<0.4f?8:0)|(RM.y>0.5f?16:0)|(DG.y<=0.f?32:0);
  q.z = (RI.z<0.05f?1:0)|(RI.z<0.2f?2:0)|(RI.z<0.3f?4:0)|(RE.z<0.4f?8:0)|(RM.z>0.5f?16:0)|(DG.z<=0.f?32:0);
  q.w = (RI.w<0.05f?1:0)|(RI.w<0.2f?2:0)|(RI.w<0.3f?4:0)|(RE.w<0.4f?8:0)|(RM.w>0.5f?16:0)|(DG.w<=0.f?32:0);
  *reinterpret_cast<uchar4*>(rb + base) = q;
}

// ============ K2: everything else, fused per 4-row band of full-width rows ============
// Row cascade per block (rel to ty):  e0/rb [-6,10) -> eas [-5,9) -> b1 [-4,8)
// -> hb [-3,7) -> eF [-2,6) -> fluid/eL [-2,6) -> cloner+out [0,4).  LDS idx = rel + off.
#define OUT 4

// fluid macros: named scalars only (no arrays -> no scratch). P = dens-nibble | grav<<4,
// carried through the swaps (and through the edge shuffles) instead of re-derived.
#define PROPS(E) ((int)((PACKD >> ((E)*4)) & 15) | ((((GMASK) >> (E)) & 1) << 4))
#define FD(M,BIT) (((M) > 0 || ((M) == 0 && ((rmb >> (BIT)) & 1))) ? 1 : 0)

#define STEPL(NE_,NP_,EC,PC,EW,PW,EE,PE,FC,FE,NDC,NDE,MOM) { \
  bool dbl = (FC) && ((EC)==el) && (NDC) && (((PC)&15) > ((PW)&15)) && ((PW)&16) && ((PC)&16); \
  bool dbr = (FE) && ((EE)==el) && (NDE) && (((PE)&15) > ((PC)&15)) && ((PE)&16) && ((PC)&16); \
  MOM += dbr ? 2 : 0; \
  NE_ = dbl ? (EW) : (dbr ? (EE) : (EC)); \
  NP_ = dbl ? (PW) : (dbr ? (PE) : (PC)); }

#define STEPR(NE_,NP_,EC,PC,EW,PW,EE,PE,FC,FW,NDC,NDW,MOM) { \
  bool dbl = !(FC) && ((EC)==el) && (NDC) && (((PC)&15) > ((PE)&15)) && ((PE)&16) && ((PC)&16); \
  bool dbr = !(FW) && ((EW)==el) && (NDW) && (((PW)&15) > ((PC)&15)) && ((PW)&16) && ((PC)&16); \
  MOM -= dbr ? 2 : 0; \
  NE_ = dbl ? (EE) : (dbr ? (EW) : (EC)); \
  NP_ = dbl ? (PE) : (dbr ? (PW) : (PC)); }

#define FDEF int f0=FD(M0,0), f1=FD(M1,1), f2=FD(M2,2), f3=FD(M3,3), \
                 f4=FD(M4,4), f5=FD(M5,5), f6=FD(M6,6), f7=FD(M7,7)

__global__ __launch_bounds__(512) void k_rest(const unsigned char* __restrict__ e0g,
                                              const unsigned char* __restrict__ rbg,
                                              const float* __restrict__ vin,
                                              float* __restrict__ out) {
  __shared__ unsigned char e0s[16][512];
  __shared__ unsigned char rbs[16][512];
  __shared__ unsigned char eas[14][512];
  __shared__ unsigned char b1s[12][512];
  __shared__ unsigned char hbs[10][512];
  __shared__ unsigned char efs[8][512];
  __shared__ unsigned char eLs[8][512];
  __shared__ signed char   nms[4][512];

  int tid = threadIdx.x;
  int blk = blockIdx.x;
  int b = blk >> 7;                 // 128 bands per batch
  int ty = (blk & 127) * OUT;
  int bbase = b * HW;
  float* vout = out + NWORLD;

  // ---- stage e0 + rb rows [ty-6, ty+10), vectorized uchar4
  {
    int rquad = tid >> 7;           // 0..3
    int c4 = (tid & 127) << 2;
    #pragma unroll
    for (int i = 0; i < 4; ++i) {
      int l = i*4 + rquad;
      int gy = (ty + l - 6) & 511;
      int gi = bbase + (gy << 9) + c4;
      *reinterpret_cast<uchar4*>(&e0s[l][c4]) = *reinterpret_cast<const uchar4*>(e0g + gi);
      *reinterpret_cast<uchar4*>(&rbs[l][c4]) = *reinterpret_cast<const uchar4*>(rbg + gi);
    }
  }
  __syncthreads();

  int x = tid;                      // absolute column for per-row phases
  int xl1 = (x + 511) & 511, xr1 = (x + 1) & 511;

  // ---- acid: eas[l] abs ty+l-5, vertical-only (wrap)
  #pragma unroll
  for (int l = 0; l < 14; ++l) {
    int ec = e0s[l+1][x], eu = e0s[l][x], ed = e0s[l+2][x];
    bool arc = (rbs[l+1][x] & 2) != 0;
    bool aru = (rbs[l][x]   & 2) != 0;
    bool ard = (rbs[l+2][x] & 2) != 0;
    bool does_acid  = (ec == E_ACID) && arc && (is_block_e(ed) || is_block_e(eu));
    bool does_block = is_block_e(ec) && ((aru && eu == E_ACID) || (ard && ed == E_ACID));
    eas[l][x] = (does_acid || does_block) ? (unsigned char)E_EMPTY : (unsigned char)ec;
  }
  __syncthreads();

  // ---- fire1 -> b1: b1[l] abs ty+l-4 (conv3x3 zero-pad on fire+lava of eas)
  #pragma unroll
  for (int l = 0; l < 12; ++l) {
    int gy = (ty + l - 4) & 511;
    bool hfn = false;
    #pragma unroll
    for (int dy = -1; dy <= 1; ++dy) {
      int yy = gy + dy; if ((unsigned)yy >= 512u) continue;
      #pragma unroll
      for (int dx = -1; dx <= 1; ++dx) {
        int xx = x + dx; if ((unsigned)xx >= 512u) continue;
        int q = eas[l+1+dy][xx];
        hfn = hfn || (q == E_FIRE) || (q == E_LAVA);
      }
    }
    int ec = eas[l+1][x];
    int rbv = rbs[l+2][x];
    bool db = (ec==E_WOOD && (rbv&1)) || (ec==E_PLANT && (rbv&2)) ||
              (ec==E_GAS  && (rbv&2)) || (ec==E_DUST);
    bool does_burn = db && hfn;
    bool db_ice = (ec==E_ICE) && (rbv&2) && hfn;
    int e1 = does_burn ? E_FIRE : (db_ice ? E_WATER : ec);
    b1s[l][x] = (unsigned char)(e1 | (does_burn?16:0) | ((ec==E_DUST && hfn)?32:0));
  }
  __syncthreads();

  // ---- hbn: hb[l] abs ty+l-3 (conv3x3 zero-pad of burnable(e1))
  #pragma unroll
  for (int l = 0; l < 10; ++l) {
    int gy = (ty + l - 3) & 511;
    int cnt = 0;
    #pragma unroll
    for (int dy = -1; dy <= 1; ++dy) {
      int yy = gy + dy; if ((unsigned)yy >= 512u) continue;
      #pragma unroll
      for (int dx = -1; dx <= 1; ++dx) {
        int xx = x + dx; if ((unsigned)xx >= 512u) continue;
        cnt += is_burnable_e(b1s[l+1+dy][xx] & 15);
      }
    }
    hbs[l][x] = (unsigned char)cnt;
  }
  __syncthreads();

  // ---- fire2 -> efs[l] abs ty+l-2 ; velocity for rows [0,OUT)
  #pragma unroll
  for (int l = 0; l < 8; ++l) {
    int gy = (ty + l - 2) & 511;
    int ifr = 0;
    #pragma unroll
    for (int dy = -1; dy <= 1; ++dy) {
      int yy = gy + dy; if ((unsigned)yy >= 512u) continue;
      #pragma unroll
      for (int dx = -1; dx <= 1; ++dx) {
        int xx = x + dx; if ((unsigned)xx >= 512u) continue;
        int hbq = hbs[l+1+dy][xx];
        int eaq = eas[l+3+dy][xx];
        int e1q = b1s[l+2+dy][xx] & 15;
        ifr += hbq * (((eaq==E_FIRE)||(eaq==E_LAVA))?1:0) + ((e1q==E_LAVA)?1:0);
      }
    }
    int e1 = b1s[l+2][x] & 15;
    int rbv = rbs[l+4][x];
    bool db_empty = (e1 == E_EMPTY) && (ifr > 0) && ((rbv & 4) != 0);
    int e2 = db_empty ? E_FIRE : e1;
    bool fire_empty = (e2 == E_FIRE) && ((rbv & 8) != 0) && (hbs[l+1][x] == 0);
    efs[l][x] = fire_empty ? (unsigned char)E_EMPTY : (unsigned char)e2;
  }
  #pragma unroll
  for (int r = 0; r < OUT; ++r) {
    int gy = ty + r;
    int fu  = b1s[r+3][x];
    int fd_ = b1s[r+5][x];
    int flf = b1s[r+4][xl1];
    int frt = b1s[r+4][xr1];
    float vy = vin[(size_t)(b*2+0)*HW + (gy<<9) + x];
    vy = vy + 2.0f*(float)((fu>>4)&1);   vy = vy - 2.0f*(float)((fd_>>4)&1);
    vy = vy + 20.0f*(float)((fu>>5)&1);  vy = vy - 20.0f*(float)((fd_>>5)&1);
    float vx = vin[(size_t)(b*2+1)*HW + (gy<<9) + x];
    vx = vx + 2.0f*(float)((flf>>4)&1);  vx = vx - 2.0f*(float)((frt>>4)&1);
    vx = vx + 20.0f*(float)((flf>>5)&1); vx = vx - 20.0f*(float)((frt>>5)&1);
    vout[(size_t)(b*2+0)*HW + (gy<<9) + x] = vy;
    vout[(size_t)(b*2+1)*HW + (gy<<9) + x] = vx;
  }
  __syncthreads();

  // ---- fluid: 8 waves, wave w owns efs row w (abs ty+w-2), registers + edge shuffles.
  {
    int w = tid >> 6, lane = tid & 63;
    uint2 ev = *reinterpret_cast<const uint2*>(&efs[w][lane << 3]);
    int E0 =  ev.x        & 255, E1 = (ev.x >> 8) & 255,
        E2 = (ev.x >> 16) & 255, E3 = (ev.x >> 24) & 255,
        E4 =  ev.y        & 255, E5 = (ev.y >> 8) & 255,
        E6 = (ev.y >> 16) & 255, E7 = (ev.y >> 24) & 255;
    uint2 qv = *reinterpret_cast<const uint2*>(&rbs[w+4][lane << 3]);
    int rmb = ((qv.x>>4)&1) | (((qv.x>>12)&1)<<1) | (((qv.x>>20)&1)<<2) | (((qv.x>>28)&1)<<3)
            | (((qv.y>>4)&1)<<4) | (((qv.y>>12)&1)<<5) | (((qv.y>>20)&1)<<6) | (((qv.y>>28)&1)<<7);
    int nd0 = (qv.x>>5)&1,  nd1 = (qv.x>>13)&1, nd2 = (qv.x>>21)&1, nd3 = (qv.x>>29)&1,
        nd4 = (qv.y>>5)&1,  nd5 = (qv.y>>13)&1, nd6 = (qv.y>>21)&1, nd7 = (qv.y>>29)&1;
    int P0=PROPS(E0), P1=PROPS(E1), P2=PROPS(E2), P3=PROPS(E3),
        P4=PROPS(E4), P5=PROPS(E5), P6=PROPS(E6), P7=PROPS(E7);
    int M0=0,M1=0,M2=0,M3=0,M4=0,M5=0,M6=0,M7=0;

    int laneL = (lane + 63) & 63, laneR = (lane + 1) & 63;
    int ndpk = nd0 | (nd7 << 1);
    int ndl = (__shfl(ndpk, laneL, 64) >> 1) & 1;
    int ndr =  __shfl(ndpk, laneR, 64) & 1;

    #pragma unroll
    for (int ei = 0; ei < 5; ++ei) {
      const int el = (ei==0) ? E_EMPTY : (ei==1) ? E_WATER : (ei==2) ? E_GAS
                   : (ei==3) ? E_LAVA  : E_ACID;
      { // fall_left
        FDEF;
        int pl_ = __shfl(E7 | (f7 << 8) | (P7 << 9), laneL, 64);
        int pr_ = __shfl(E0 | (f0 << 8) | (P0 << 9), laneR, 64);
        int EBL = pl_ & 255, PBL = (pl_ >> 9) & 31;
        int EBR = pr_ & 255, FBR = (pr_ >> 8) & 1, PBR = (pr_ >> 9) & 31;
        int N0,N1,N2,N3,N4,N5,N6,N7, Q0,Q1,Q2,Q3,Q4,Q5,Q6,Q7;
        STEPL(N0,Q0,E0,P0,EBL,PBL,E1,P1,f0,f1, nd0,nd1,M0);
        STEPL(N1,Q1,E1,P1,E0, P0, E2,P2,f1,f2, nd1,nd2,M1);
        STEPL(N2,Q2,E2,P2,E1, P1, E3,P3,f2,f3, nd2,nd3,M2);
        STEPL(N3,Q3,E3,P3,E2, P2, E4,P4,f3,f4, nd3,nd4,M3);
        STEPL(N4,Q4,E4,P4,E3, P3, E5,P5,f4,f5, nd4,nd5,M4);
        STEPL(N5,Q5,E5,P5,E4, P4, E6,P6,f5,f6, nd5,nd6,M5);
        STEPL(N6,Q6,E6,P6,E5, P5, E7,P7,f6,f7, nd6,nd7,M6);
        STEPL(N7,Q7,E7,P7,E6, P6,EBR,PBR,f7,FBR,nd7,ndr,M7);
        E0=N0;E1=N1;E2=N2;E3=N3;E4=N4;E5=N5;E6=N6;E7=N7;
        P0=Q0;P1=Q1;P2=Q2;P3=Q3;P4=Q4;P5=Q5;P6=Q6;P7=Q7;
      }
      { // fall_right
        FDEF;
        int pl_ = __shfl(E7 | (f7 << 8) | (P7 << 9), laneL, 64);
        int pr_ = __shfl(E0 | (f0 << 8) | (P0 << 9), laneR, 64);
        int EBL = pl_ & 255, FBL = (pl_ >> 8) & 1, PBL = (pl_ >> 9) & 31;
        int EBR = pr_ & 255, PBR = (pr_ >> 9) & 31;
        int N0,N1,N2,N3,N4,N5,N6,N7, Q0,Q1,Q2,Q3,Q4,Q5,Q6,Q7;
        STEPR(N0,Q0,E0,P0,EBL,PBL,E1,P1,f0,FBL,nd0,ndl,M0);
        STEPR(N1,Q1,E1,P1,E0, P0, E2,P2,f1,f0, nd1,nd0,M1);
        STEPR(N2,Q2,E2,P2,E1, P1, E3,P3,f2,f1, nd2,nd1,M2);
        STEPR(N3,Q3,E3,P3,E2, P2, E4,P4,f3,f2, nd3,nd2,M3);
        STEPR(N4,Q4,E4,P4,E3, P3, E5,P5,f4,f3, nd4,nd3,M4);
        STEPR(N5,Q5,E5,P5,E4, P4, E6,P6,f5,f4, nd5,nd4,M5);
        STEPR(N6,Q6,E6,P6,E5, P5, E7,P7,f6,f5, nd6,nd5,M6);
        STEPR(N7,Q7,E7,P7,E6, P6,EBR,PBR,f7,f6, nd7,nd6,M7);
        E0=N0;E1=N1;E2=N2;E3=N3;E4=N4;E5=N5;E6=N6;E7=N7;
        P0=Q0;P1=Q1;P2=Q2;P3=Q3;P4=Q4;P5=Q5;P6=Q6;P7=Q7;
      }
    }
    unsigned int w0 = (unsigned)E0 | ((unsigned)E1<<8) | ((unsigned)E2<<16) | ((unsigned)E3<<24);
    unsigned int w1 = (unsigned)E4 | ((unsigned)E5<<8) | ((unsigned)E6<<16) | ((unsigned)E7<<24);
    *reinterpret_cast<uint2*>(&eLs[w][lane << 3]) = make_uint2(w0, w1);
    if (w >= 2 && w < 2 + OUT) {
      unsigned int m0 = (M0&255) | ((M1&255)<<8) | ((M2&255)<<16) | ((unsigned)(M3&255)<<24);
      unsigned int m1 = (M4&255) | ((M5&255)<<8) | ((M6&255)<<16) | ((unsigned)(M7&255)<<24);
      *reinterpret_cast<uint2*>(reinterpret_cast<unsigned char*>(&nms[w-2][0]) + (lane << 3)) =
          make_uint2(m0, m1);
    }
  }
  __syncthreads();

  // ---- cloner + expand to 18-ch output. thread t -> quad (row r=t>>7, x0=(t&127)*4).
  {
    int r = tid >> 7;               // 0..3
    int x0 = (tid & 127) << 2;
    const int DY[4] = {1, -1, 0, 0};
    const int DX[4] = {0, 0, -1, 1};
    int eo[4]; float mom[4], cao[4];
    #pragma unroll
    for (int k = 0; k < 4; ++k) {
      int xx = x0 + k;
      int ry = r + 2;               // eLs row of this cell
      int ec = eLs[ry][xx];
      float m = (float)nms[r][xx];
      int e = ec; float ca = 0.f;
      if (ec == E_CLONER) {
        int c = eLs[ry+1][xx];
        if (c==0||c==13) c = eLs[ry-1][xx];
        if (c==0||c==13) c = eLs[ry][(xx+511)&511];
        if (c==0||c==13) c = eLs[ry][(xx+1)&511];
        ca = (float)c;
      } else if (ec == E_EMPTY) {
        #pragma unroll
        for (int d = 0; d < 4; ++d) {
          int qy = ry + DY[d], qx = (xx + DX[d]) & 511;
          if (eLs[qy][qx] == E_CLONER) {
            int c = eLs[qy+1][qx];
            if (c==0||c==13) c = eLs[qy-1][qx];
            if (c==0||c==13) c = eLs[qy][(qx+511)&511];
            if (c==0||c==13) c = eLs[qy][(qx+1)&511];
            if (c != 0 && c != 13) { e = c; m = 0.f; break; }
          }
        }
      }
      eo[k] = e; mom[k] = m; cao[k] = ca;
    }
    float* ob = out + (size_t)b * CH * HW + ((ty + r) << 9) + x0;
    #pragma unroll
    for (int c = 0; c < 14; ++c) {
      float4 v = make_float4(eo[0]==c ? 1.f : 0.f, eo[1]==c ? 1.f : 0.f,
                             eo[2]==c ? 1.f : 0.f, eo[3]==c ? 1.f : 0.f);
      *reinterpret_cast<float4*>(ob + (size_t)c * HW) = v;
    }
    *reinterpret_cast<float4*>(ob + (size_t)14*HW) =
        make_float4(c_dens[eo[0]], c_dens[eo[1]], c_dens[eo[2]], c_dens[eo[3]]);
    *reinterpret_cast<float4*>(ob + (size_t)15*HW) =
        make_float4(c_grav[eo[0]], c_grav[eo[1]], c_grav[eo[2]], c_grav[eo[3]]);
    *reinterpret_cast<float4*>(ob + (size_t)16*HW) =
        make_float4(mom[0], mom[1], mom[2], mom[3]);
    *reinterpret_cast<float4*>(ob + (size_t)17*HW) =
        make_float4(cao[0], cao[1], cao[2], cao[3]);
  }
}

extern "C" void kernel_launch(void* const* d_in, const int* in_sizes, int n_in,
                              void* d_out, int out_size, void* d_ws, size_t ws_size,
                              hipStream_t stream) {
  const float* world = (const float*)d_in[0];
  const float* rm    = (const float*)d_in[1];
  const float* ri    = (const float*)d_in[2];
  const float* re    = (const float*)d_in[3];
  const float* vel   = (const float*)d_in[4];
  const float* dg    = (const float*)d_in[5];
  float* out = (float*)d_out;

  char* ws = (char*)d_ws;
  unsigned char* e0 = (unsigned char*)ws;
  unsigned char* rb = e0 + NPIX;

  hipLaunchKernelGGL(k_prep, dim3(NPIX/1024), dim3(256), 0, stream,
                     world, ri, re, rm, dg, e0, rb);
  hipLaunchKernelGGL(k_rest, dim3(4*(512/OUT)), dim3(512), 0, stream,
                     e0, rb, vel, out);
}